// Round 1
// baseline (842.138 us; speedup 1.0000x reference)
//
#include <hip/hip_runtime.h>
#include <hip/hip_bf16.h>

// ---------- helpers ----------
__device__ __forceinline__ float b2f(unsigned short u) {
  return __uint_as_float(((unsigned int)u) << 16);
}
__device__ __forceinline__ unsigned short f2b(float f) {
  unsigned int x = __float_as_uint(f);
  unsigned int r = x + 0x7FFFu + ((x >> 16) & 1u);  // RNE
  return (unsigned short)(r >> 16);
}

// ---------- dtype detection ----------
// hdr[0]: 0 = floats are bf16, 1 = floats are f32
// hdr[1]: 0 = edge_index int32, 1 = int64
__global__ void detect_kernel(const void* __restrict__ x_raw,
                              const void* __restrict__ idx_raw,
                              int* __restrict__ hdr) {
  int lane = threadIdx.x;  // 64 threads
  // Float detect: read even-index bf16 slots. If underlying data is f32,
  // those slots are low mantissa bits -> uniform random exponent field.
  const unsigned short* xb = (const unsigned short*)x_raw;
  unsigned short u = xb[2 * lane];
  int e = (u >> 7) & 0xFF;
  bool sane = ((u & 0x7FFFu) == 0) || (e >= 107 && e <= 137);  // |v| in [2^-20, 2^10]
  unsigned long long m = __ballot(sane);
  // Int detect: odd int32 words of int64 data are all zero (values < 2^31).
  const int* ib = (const int*)idx_raw;
  int v = ib[2 * lane + 1];
  unsigned long long m2 = __ballot(v != 0);
  if (lane == 0) {
    hdr[0] = (__popcll(m) >= 32) ? 0 : 1;
    hdr[1] = (m2 == 0ull) ? 1 : 0;
  }
}

// ---------- canonicalization ----------
__global__ void convert_idx_kernel(const int* __restrict__ idx_raw,
                                   const int* __restrict__ hdr,
                                   int* __restrict__ src, int* __restrict__ dst,
                                   int n_edges) {
  int e = blockIdx.x * blockDim.x + threadIdx.x;
  if (e >= n_edges) return;
  if (hdr[1]) {  // int64 (little-endian low words)
    src[e] = idx_raw[2 * e];
    dst[e] = idx_raw[2 * (n_edges + e)];
  } else {
    src[e] = idx_raw[e];
    dst[e] = idx_raw[n_edges + e];
  }
}

__global__ void convert_w_kernel(const void* __restrict__ W1l, const void* __restrict__ W1r,
                                 const void* __restrict__ W2l, const void* __restrict__ W2r,
                                 const void* __restrict__ b1, const void* __restrict__ b2,
                                 const int* __restrict__ hdr,
                                 float* __restrict__ W1l_f, float* __restrict__ W1r_f,
                                 float* __restrict__ W2l_f, float* __restrict__ W2r_f,
                                 float* __restrict__ b1_f, float* __restrict__ b2_f) {
  int i = blockIdx.x * blockDim.x + threadIdx.x;
  const void* s; float* d; int off;
  if (i < 8192)       { s = W1l; d = W1l_f; off = i; }
  else if (i < 16384) { s = W1r; d = W1r_f; off = i - 8192; }
  else if (i < 32768) { s = W2l; d = W2l_f; off = i - 16384; }
  else if (i < 49152) { s = W2r; d = W2r_f; off = i - 32768; }
  else if (i < 49280) { s = b1;  d = b1_f;  off = i - 49152; }
  else if (i < 49408) { s = b2;  d = b2_f;  off = i - 49280; }
  else return;
  float v = hdr[0] ? ((const float*)s)[off] : b2f(((const unsigned short*)s)[off]);
  d[off] = v;
}

__global__ void convert_x_kernel(const void* __restrict__ x_raw,
                                 const int* __restrict__ hdr,
                                 unsigned short* __restrict__ xc, int n_elems) {
  int i = blockIdx.x * blockDim.x + threadIdx.x;
  if (i >= n_elems) return;
  xc[i] = hdr[0] ? f2b(((const float*)x_raw)[i]) : ((const unsigned short*)x_raw)[i];
}

// ---------- CSR build ----------
__global__ void hist_kernel(const int* __restrict__ dst, int* __restrict__ cnt, int n_edges) {
  int e = blockIdx.x * blockDim.x + threadIdx.x;
  if (e < n_edges) atomicAdd(&cnt[dst[e]], 1);
}

__global__ void scan_kernel(const int* __restrict__ cnt, int* __restrict__ row_start,
                            int* __restrict__ cursor, float* __restrict__ deg_inv,
                            int n_nodes) {
  __shared__ int wsum[16];
  int tid = threadIdx.x, lane = tid & 63, wid = tid >> 6;
  int base = 0;
  for (int start = 0; start < n_nodes; start += 1024) {
    int i = start + tid;
    int v = (i < n_nodes) ? cnt[i] : 0;
    int isc = v;
    #pragma unroll
    for (int off = 1; off < 64; off <<= 1) {
      int t = __shfl_up(isc, off, 64);
      if (lane >= off) isc += t;
    }
    if (lane == 63) wsum[wid] = isc;
    __syncthreads();
    int wbase = 0, ctot = 0;
    #pragma unroll
    for (int w = 0; w < 16; ++w) {
      int s = wsum[w];
      if (w < wid) wbase += s;
      ctot += s;
    }
    if (i < n_nodes) {
      int excl = base + wbase + isc - v;
      row_start[i] = excl;
      cursor[i]    = excl;
      deg_inv[i]   = 1.0f / (float)((v > 1) ? v : 1);
    }
    base += ctot;
    __syncthreads();
  }
  if (tid == 0) row_start[n_nodes] = base;
}

__global__ void fill_kernel(const int* __restrict__ src, const int* __restrict__ dst,
                            int* __restrict__ cursor, int* __restrict__ col, int n_edges) {
  int e = blockIdx.x * blockDim.x + threadIdx.x;
  if (e >= n_edges) return;
  int pos = atomicAdd(&cursor[dst[e]], 1);
  col[pos] = src[e];
}

// ---------- mean-aggregation gathers (no float atomics) ----------
__global__ void gather1_kernel(const unsigned short* __restrict__ xc,
                               const int* __restrict__ row_start,
                               const int* __restrict__ col,
                               const float* __restrict__ deg_inv,
                               unsigned short* __restrict__ agg1, int n_nodes) {
  int f = threadIdx.x & 63;
  int n = blockIdx.x * 4 + (threadIdx.x >> 6);  // one wave per node
  if (n >= n_nodes) return;
  int beg = row_start[n], end = row_start[n + 1];
  float acc = 0.f;
  int i = beg;
  for (; i + 1 < end; i += 2) {
    int s0 = col[i], s1 = col[i + 1];
    float v0 = b2f(xc[s0 * 64 + f]);
    float v1 = b2f(xc[s1 * 64 + f]);
    acc += v0 + v1;
  }
  if (i < end) acc += b2f(xc[col[i] * 64 + f]);
  agg1[n * 64 + f] = f2b(acc * deg_inv[n]);
}

__global__ void gather2_kernel(const unsigned short* __restrict__ h,
                               const int* __restrict__ row_start,
                               const int* __restrict__ col,
                               const float* __restrict__ deg_inv,
                               unsigned short* __restrict__ agg2, int n_nodes) {
  int f = threadIdx.x & 127;
  int n = blockIdx.x * 2 + (threadIdx.x >> 7);  // two waves per node
  if (n >= n_nodes) return;
  int beg = row_start[n], end = row_start[n + 1];
  float acc = 0.f;
  int i = beg;
  for (; i + 1 < end; i += 2) {
    int s0 = col[i], s1 = col[i + 1];
    float v0 = b2f(h[s0 * 128 + f]);
    float v1 = b2f(h[s1 * 128 + f]);
    acc += v0 + v1;
  }
  if (i < end) acc += b2f(h[col[i] * 128 + f]);
  agg2[n * 128 + f] = f2b(acc * deg_inv[n]);
}

// ---------- fused concat-GEMM: C = act([A1|A2] @ [Wl|Wr]^T + b) ----------
// A bf16 [N,K*], W f32 [128,K*] row-major. 128n x 128j per block, 8x8 regtile.
template <int K1, int K2, bool RELU, bool FINAL>
__global__ __launch_bounds__(256, 2) void gemm_cat(
    const unsigned short* __restrict__ A1, const unsigned short* __restrict__ A2,
    const float* __restrict__ Wl, const float* __restrict__ Wr,
    const float* __restrict__ bias,
    unsigned short* __restrict__ Cb, void* __restrict__ Cf,
    const int* __restrict__ hdr, int n_nodes) {
  // k-quad layouts, 17-quad row pad -> <=2-way LDS bank conflicts (free)
  __shared__ float4 Wq[128 * 17];  // [j][kq]
  __shared__ float4 Fq[128 * 17];  // [nl][kq]
  const int tid = threadIdx.x;
  const int tj = tid & 15;   // j = tj + 16u  (stride-16 thread tiling)
  const int tn = tid >> 4;   // n = tn + 16i
  const int nb = blockIdx.x * 128;
  float acc[8][8];
  #pragma unroll
  for (int i = 0; i < 8; ++i)
    #pragma unroll
    for (int u = 0; u < 8; ++u) acc[i][u] = 0.f;

  const int NCHUNK = (K1 + K2) / 64;
  for (int c = 0; c < NCHUNK; ++c) {
    const bool first = (c * 64) < K1;
    const float* W = first ? Wl : Wr;
    const unsigned short* A = first ? A1 : A2;
    const int kb = first ? c * 64 : c * 64 - K1;
    const int Krow = first ? K1 : K2;
    __syncthreads();
    #pragma unroll
    for (int t = 0; t < 8; ++t) {  // stage W chunk: 128j x 16 quads
      int idx = t * 256 + tid;
      int kq = idx & 15, j = idx >> 4;
      Wq[j * 17 + kq] = *(const float4*)&W[j * Krow + kb + kq * 4];
    }
    #pragma unroll
    for (int t = 0; t < 8; ++t) {  // stage feature chunk, bf16 -> f32
      int idx = t * 256 + tid;
      int kq = idx & 15, nl = idx >> 4;
      int n = nb + nl;
      float4 v = make_float4(0.f, 0.f, 0.f, 0.f);
      if (n < n_nodes) {
        ushort4 us = *(const ushort4*)&A[n * Krow + kb + kq * 4];
        v = make_float4(b2f(us.x), b2f(us.y), b2f(us.z), b2f(us.w));
      }
      Fq[nl * 17 + kq] = v;
    }
    __syncthreads();
    for (int kq = 0; kq < 16; ++kq) {
      float4 w[8], f[8];
      #pragma unroll
      for (int u = 0; u < 8; ++u) w[u] = Wq[(tj + u * 16) * 17 + kq];
      #pragma unroll
      for (int i = 0; i < 8; ++i) f[i] = Fq[(tn + i * 16) * 17 + kq];
      #pragma unroll
      for (int i = 0; i < 8; ++i)
        #pragma unroll
        for (int u = 0; u < 8; ++u) {
          acc[i][u] = fmaf(f[i].x, w[u].x, acc[i][u]);
          acc[i][u] = fmaf(f[i].y, w[u].y, acc[i][u]);
          acc[i][u] = fmaf(f[i].z, w[u].z, acc[i][u]);
          acc[i][u] = fmaf(f[i].w, w[u].w, acc[i][u]);
        }
    }
  }
  const bool f32out = FINAL && (hdr[0] == 1);
  #pragma unroll
  for (int i = 0; i < 8; ++i) {
    int n = nb + tn + i * 16;
    if (n >= n_nodes) continue;
    #pragma unroll
    for (int u = 0; u < 8; ++u) {
      int j = tj + u * 16;
      float v = acc[i][u] + bias[j];
      if (RELU) v = fmaxf(v, 0.f);
      if (FINAL) {
        if (f32out) ((float*)Cf)[n * 128 + j] = v;
        else ((unsigned short*)Cf)[n * 128 + j] = f2b(v);
      } else {
        Cb[n * 128 + j] = f2b(v);
      }
    }
  }
}

// ---------- launch ----------
extern "C" void kernel_launch(void* const* d_in, const int* in_sizes, int n_in,
                              void* d_out, int out_size, void* d_ws, size_t ws_size,
                              hipStream_t stream) {
  const void* x_raw  = d_in[0];
  const int* idx_raw = (const int*)d_in[1];
  const void* W1l = d_in[2];
  const void* b1  = d_in[3];
  const void* W1r = d_in[4];
  const void* W2l = d_in[5];
  const void* b2  = d_in[6];
  const void* W2r = d_in[7];
  const int N = in_sizes[0] / 64;
  const int E = in_sizes[1] / 2;

  char* ws = (char*)d_ws;
  size_t off = 0;
  auto alloc = [&](size_t bytes) {
    char* p = ws + off;
    off = (off + bytes + 511) & ~((size_t)511);
    return p;
  };
  int* hdr        = (int*)alloc(512);
  int* srcc       = (int*)alloc((size_t)E * 4);
  int* dstc       = (int*)alloc((size_t)E * 4);
  int* row_start  = (int*)alloc(((size_t)N + 1) * 4);
  int* cursor     = (int*)alloc((size_t)N * 4);
  int* cnt        = (int*)alloc((size_t)N * 4);
  int* col        = (int*)alloc((size_t)E * 4);
  float* deg_inv  = (float*)alloc((size_t)N * 4);
  float* W1l_f    = (float*)alloc(32768);
  float* W1r_f    = (float*)alloc(32768);
  float* W2l_f    = (float*)alloc(65536);
  float* W2r_f    = (float*)alloc(65536);
  float* b1_f     = (float*)alloc(512);
  float* b2_f     = (float*)alloc(512);
  unsigned short* xc   = (unsigned short*)alloc((size_t)N * 64 * 2);
  unsigned short* agg1 = (unsigned short*)alloc((size_t)N * 64 * 2);
  unsigned short* hbuf = (unsigned short*)alloc((size_t)N * 128 * 2);
  unsigned short* agg2 = (unsigned short*)alloc((size_t)N * 128 * 2);

  detect_kernel<<<1, 64, 0, stream>>>(x_raw, idx_raw, hdr);
  hipMemsetAsync(cnt, 0, (size_t)N * 4, stream);
  convert_idx_kernel<<<(E + 255) / 256, 256, 0, stream>>>(idx_raw, hdr, srcc, dstc, E);
  convert_w_kernel<<<(49408 + 255) / 256, 256, 0, stream>>>(
      W1l, W1r, W2l, W2r, b1, b2, hdr, W1l_f, W1r_f, W2l_f, W2r_f, b1_f, b2_f);
  convert_x_kernel<<<(N * 64 + 255) / 256, 256, 0, stream>>>(x_raw, hdr, xc, N * 64);
  hist_kernel<<<(E + 255) / 256, 256, 0, stream>>>(dstc, cnt, E);
  scan_kernel<<<1, 1024, 0, stream>>>(cnt, row_start, cursor, deg_inv, N);
  fill_kernel<<<(E + 255) / 256, 256, 0, stream>>>(srcc, dstc, cursor, col, E);
  gather1_kernel<<<(N + 3) / 4, 256, 0, stream>>>(xc, row_start, col, deg_inv, agg1, N);
  gemm_cat<64, 64, true, false><<<(N + 127) / 128, 256, 0, stream>>>(
      agg1, xc, W1l_f, W1r_f, b1_f, hbuf, nullptr, hdr, N);
  gather2_kernel<<<(N + 1) / 2, 256, 0, stream>>>(hbuf, row_start, col, deg_inv, agg2, N);
  gemm_cat<128, 128, false, true><<<(N + 127) / 128, 256, 0, stream>>>(
      agg2, hbuf, W2l_f, W2r_f, b2_f, nullptr, d_out, hdr, N);
}

// Round 2
// 589.579 us; speedup vs baseline: 1.4284x; 1.4284x over previous
//
#include <hip/hip_runtime.h>
#include <hip/hip_bf16.h>

// ---------- helpers ----------
__device__ __forceinline__ float b2f(unsigned short u) {
  return __uint_as_float(((unsigned int)u) << 16);
}
__device__ __forceinline__ unsigned short f2b(float f) {
  unsigned int x = __float_as_uint(f);
  unsigned int r = x + 0x7FFFu + ((x >> 16) & 1u);  // RNE
  return (unsigned short)(r >> 16);
}
__device__ __forceinline__ unsigned int pack2(float lo, float hi) {
  return (unsigned int)f2b(lo) | ((unsigned int)f2b(hi) << 16);
}

// ---------- dtype detection ----------
// hdr[0]: 0 = floats are bf16, 1 = floats are f32
// hdr[1]: 0 = edge_index int32, 1 = int64
__global__ void detect_kernel(const void* __restrict__ x_raw,
                              const void* __restrict__ idx_raw,
                              int* __restrict__ hdr) {
  int lane = threadIdx.x;  // 64 threads
  const unsigned short* xb = (const unsigned short*)x_raw;
  unsigned short u = xb[2 * lane];
  int e = (u >> 7) & 0xFF;
  bool sane = ((u & 0x7FFFu) == 0) || (e >= 107 && e <= 137);
  unsigned long long m = __ballot(sane);
  const int* ib = (const int*)idx_raw;
  int v = ib[2 * lane + 1];
  unsigned long long m2 = __ballot(v != 0);
  if (lane == 0) {
    hdr[0] = (__popcll(m) >= 32) ? 0 : 1;
    hdr[1] = (m2 == 0ull) ? 1 : 0;
  }
}

// ---------- canonicalize indices + degree histogram (fused) ----------
__global__ void convert_idx_hist_kernel(const int* __restrict__ idx_raw,
                                        const int* __restrict__ hdr,
                                        int* __restrict__ src, int* __restrict__ dst,
                                        int* __restrict__ cnt, int n_edges) {
  int e = blockIdx.x * blockDim.x + threadIdx.x;
  if (e >= n_edges) return;
  int s, d;
  if (hdr[1]) {  // int64 little-endian low words
    s = idx_raw[2 * e];
    d = idx_raw[2 * (n_edges + e)];
  } else {
    s = idx_raw[e];
    d = idx_raw[n_edges + e];
  }
  src[e] = s;
  dst[e] = d;
  atomicAdd(&cnt[d], 1);
}

__global__ void convert_w_kernel(const void* __restrict__ W1l, const void* __restrict__ W1r,
                                 const void* __restrict__ W2l, const void* __restrict__ W2r,
                                 const void* __restrict__ b1, const void* __restrict__ b2,
                                 const int* __restrict__ hdr,
                                 float* __restrict__ W1l_f, float* __restrict__ W1r_f,
                                 float* __restrict__ W2l_f, float* __restrict__ W2r_f,
                                 float* __restrict__ b1_f, float* __restrict__ b2_f) {
  int i = blockIdx.x * blockDim.x + threadIdx.x;
  const void* s; float* d; int off;
  if (i < 8192)       { s = W1l; d = W1l_f; off = i; }
  else if (i < 16384) { s = W1r; d = W1r_f; off = i - 8192; }
  else if (i < 32768) { s = W2l; d = W2l_f; off = i - 16384; }
  else if (i < 49152) { s = W2r; d = W2r_f; off = i - 32768; }
  else if (i < 49280) { s = b1;  d = b1_f;  off = i - 49152; }
  else if (i < 49408) { s = b2;  d = b2_f;  off = i - 49280; }
  else return;
  float v = hdr[0] ? ((const float*)s)[off] : b2f(((const unsigned short*)s)[off]);
  d[off] = v;
}

__global__ void convert_x_kernel(const void* __restrict__ x_raw,
                                 const int* __restrict__ hdr,
                                 unsigned short* __restrict__ xc, int n_elems) {
  int i = blockIdx.x * blockDim.x + threadIdx.x;
  if (i >= n_elems) return;
  xc[i] = hdr[0] ? f2b(((const float*)x_raw)[i]) : ((const unsigned short*)x_raw)[i];
}

// ---------- multi-block exclusive scan of cnt -> row_start / cursor / deg_inv ----------
// Phase 1: per-block (2048 elems) sums
__global__ __launch_bounds__(256) void scan_sums_kernel(const int* __restrict__ cnt,
                                                        int* __restrict__ blockSums, int n) {
  __shared__ int ws[4];
  int tid = threadIdx.x, lane = tid & 63, wid = tid >> 6;
  int base = blockIdx.x * 2048 + tid * 8;
  int s = 0;
  #pragma unroll
  for (int t = 0; t < 8; ++t) {
    int i = base + t;
    if (i < n) s += cnt[i];
  }
  #pragma unroll
  for (int m = 1; m < 64; m <<= 1) s += __shfl_xor(s, m, 64);
  if (lane == 0) ws[wid] = s;
  __syncthreads();
  if (tid == 0) blockSums[blockIdx.x] = ws[0] + ws[1] + ws[2] + ws[3];
}

// Phase 2: single-wave exclusive scan of block sums
__global__ void scan_offsets_kernel(const int* __restrict__ blockSums,
                                    int* __restrict__ blockOffs, int nb) {
  int lane = threadIdx.x;  // 64
  int carry = 0;
  for (int start = 0; start < nb; start += 64) {
    int i = start + lane;
    int v = (i < nb) ? blockSums[i] : 0;
    int isc = v;
    #pragma unroll
    for (int off = 1; off < 64; off <<= 1) {
      int t = __shfl_up(isc, off, 64);
      if (lane >= off) isc += t;
    }
    if (i < nb) blockOffs[i] = carry + isc - v;
    carry += __shfl(isc, 63, 64);
  }
}

// Phase 3: emit row_start/cursor/deg_inv
__global__ __launch_bounds__(256) void scan_emit_kernel(const int* __restrict__ cnt,
                                                        const int* __restrict__ blockOffs,
                                                        int* __restrict__ row_start,
                                                        int* __restrict__ cursor,
                                                        float* __restrict__ deg_inv,
                                                        int n, int n_edges) {
  __shared__ int ws[4];
  int tid = threadIdx.x, lane = tid & 63, wid = tid >> 6;
  int base = blockIdx.x * 2048 + tid * 8;
  int v[8];
  int s = 0;
  #pragma unroll
  for (int t = 0; t < 8; ++t) {
    int i = base + t;
    v[t] = (i < n) ? cnt[i] : 0;
    s += v[t];
  }
  int isc = s;
  #pragma unroll
  for (int off = 1; off < 64; off <<= 1) {
    int t = __shfl_up(isc, off, 64);
    if (lane >= off) isc += t;
  }
  if (lane == 63) ws[wid] = isc;
  __syncthreads();
  int wb = 0;
  #pragma unroll
  for (int w = 0; w < 4; ++w)
    if (w < wid) wb += ws[w];
  int excl = blockOffs[blockIdx.x] + wb + isc - s;
  #pragma unroll
  for (int t = 0; t < 8; ++t) {
    int i = base + t;
    if (i < n) {
      row_start[i] = excl;
      cursor[i] = excl;
      deg_inv[i] = 1.0f / (float)((v[t] > 1) ? v[t] : 1);
      excl += v[t];
    }
  }
  if (blockIdx.x == 0 && tid == 0) row_start[n] = n_edges;  // total degree == E
}

__global__ void fill_kernel(const int* __restrict__ src, const int* __restrict__ dst,
                            int* __restrict__ cursor, int* __restrict__ col, int n_edges) {
  int e = blockIdx.x * blockDim.x + threadIdx.x;
  if (e >= n_edges) return;
  int pos = atomicAdd(&cursor[dst[e]], 1);
  col[pos] = src[e];
}

// ---------- vectorized mean-aggregation gathers ----------
// gather1: rows of 64 bf16 (128B = 8 x uint4). Lane layout: rg=lane>>3 (edge
// slot, 8 edges/load-inst), fq=lane&7 (8 features each). One wave per node.
__global__ __launch_bounds__(256) void gather1_kernel(
    const unsigned short* __restrict__ xc, const int* __restrict__ row_start,
    const int* __restrict__ col, const float* __restrict__ deg_inv,
    unsigned short* __restrict__ agg1, int n_nodes) {
  int lane = threadIdx.x & 63;
  int n = blockIdx.x * 4 + (threadIdx.x >> 6);
  if (n >= n_nodes) return;
  int rg = lane >> 3, fq = lane & 7;
  int beg = row_start[n], end = row_start[n + 1];
  float a[8];
  #pragma unroll
  for (int t = 0; t < 8; ++t) a[t] = 0.f;
  int i = beg;
  for (; i + 15 < end; i += 16) {  // 16 edges in flight per wave
    int s0 = col[i + rg], s1 = col[i + 8 + rg];
    uint4 p = *(const uint4*)(xc + (size_t)s0 * 64 + fq * 8);
    uint4 q = *(const uint4*)(xc + (size_t)s1 * 64 + fq * 8);
    a[0] += b2f(p.x & 0xFFFF); a[1] += b2f(p.x >> 16);
    a[2] += b2f(p.y & 0xFFFF); a[3] += b2f(p.y >> 16);
    a[4] += b2f(p.z & 0xFFFF); a[5] += b2f(p.z >> 16);
    a[6] += b2f(p.w & 0xFFFF); a[7] += b2f(p.w >> 16);
    a[0] += b2f(q.x & 0xFFFF); a[1] += b2f(q.x >> 16);
    a[2] += b2f(q.y & 0xFFFF); a[3] += b2f(q.y >> 16);
    a[4] += b2f(q.z & 0xFFFF); a[5] += b2f(q.z >> 16);
    a[6] += b2f(q.w & 0xFFFF); a[7] += b2f(q.w >> 16);
  }
  for (; i < end; i += 8) {
    if (i + rg < end) {
      int s0 = col[i + rg];
      uint4 p = *(const uint4*)(xc + (size_t)s0 * 64 + fq * 8);
      a[0] += b2f(p.x & 0xFFFF); a[1] += b2f(p.x >> 16);
      a[2] += b2f(p.y & 0xFFFF); a[3] += b2f(p.y >> 16);
      a[4] += b2f(p.z & 0xFFFF); a[5] += b2f(p.z >> 16);
      a[6] += b2f(p.w & 0xFFFF); a[7] += b2f(p.w >> 16);
    }
  }
  #pragma unroll
  for (int m = 8; m < 64; m <<= 1)
    #pragma unroll
    for (int t = 0; t < 8; ++t) a[t] += __shfl_xor(a[t], m, 64);
  if (rg == 0) {
    float di = deg_inv[n];
    uint4 o;
    o.x = pack2(a[0] * di, a[1] * di);
    o.y = pack2(a[2] * di, a[3] * di);
    o.z = pack2(a[4] * di, a[5] * di);
    o.w = pack2(a[6] * di, a[7] * di);
    *(uint4*)(agg1 + (size_t)n * 64 + fq * 8) = o;
  }
}

// gather2: rows of 128 bf16 (256B = 16 x uint4). rg=lane>>4 (4 edges/inst),
// fq=lane&15.
__global__ __launch_bounds__(256) void gather2_kernel(
    const unsigned short* __restrict__ h, const int* __restrict__ row_start,
    const int* __restrict__ col, const float* __restrict__ deg_inv,
    unsigned short* __restrict__ agg2, int n_nodes) {
  int lane = threadIdx.x & 63;
  int n = blockIdx.x * 4 + (threadIdx.x >> 6);
  if (n >= n_nodes) return;
  int rg = lane >> 4, fq = lane & 15;
  int beg = row_start[n], end = row_start[n + 1];
  float a[8];
  #pragma unroll
  for (int t = 0; t < 8; ++t) a[t] = 0.f;
  int i = beg;
  for (; i + 7 < end; i += 8) {  // 8 edges in flight per wave
    int s0 = col[i + rg], s1 = col[i + 4 + rg];
    uint4 p = *(const uint4*)(h + (size_t)s0 * 128 + fq * 8);
    uint4 q = *(const uint4*)(h + (size_t)s1 * 128 + fq * 8);
    a[0] += b2f(p.x & 0xFFFF); a[1] += b2f(p.x >> 16);
    a[2] += b2f(p.y & 0xFFFF); a[3] += b2f(p.y >> 16);
    a[4] += b2f(p.z & 0xFFFF); a[5] += b2f(p.z >> 16);
    a[6] += b2f(p.w & 0xFFFF); a[7] += b2f(p.w >> 16);
    a[0] += b2f(q.x & 0xFFFF); a[1] += b2f(q.x >> 16);
    a[2] += b2f(q.y & 0xFFFF); a[3] += b2f(q.y >> 16);
    a[4] += b2f(q.z & 0xFFFF); a[5] += b2f(q.z >> 16);
    a[6] += b2f(q.w & 0xFFFF); a[7] += b2f(q.w >> 16);
  }
  for (; i < end; i += 4) {
    if (i + rg < end) {
      int s0 = col[i + rg];
      uint4 p = *(const uint4*)(h + (size_t)s0 * 128 + fq * 8);
      a[0] += b2f(p.x & 0xFFFF); a[1] += b2f(p.x >> 16);
      a[2] += b2f(p.y & 0xFFFF); a[3] += b2f(p.y >> 16);
      a[4] += b2f(p.z & 0xFFFF); a[5] += b2f(p.z >> 16);
      a[6] += b2f(p.w & 0xFFFF); a[7] += b2f(p.w >> 16);
    }
  }
  #pragma unroll
  for (int m = 16; m < 64; m <<= 1)
    #pragma unroll
    for (int t = 0; t < 8; ++t) a[t] += __shfl_xor(a[t], m, 64);
  if (rg == 0) {
    float di = deg_inv[n];
    uint4 o;
    o.x = pack2(a[0] * di, a[1] * di);
    o.y = pack2(a[2] * di, a[3] * di);
    o.z = pack2(a[4] * di, a[5] * di);
    o.w = pack2(a[6] * di, a[7] * di);
    *(uint4*)(agg2 + (size_t)n * 128 + fq * 8) = o;
  }
}

// ---------- fused concat-GEMM: C = act([A1|A2] @ [Wl|Wr]^T + b) ----------
template <int K1, int K2, bool RELU, bool FINAL>
__global__ __launch_bounds__(256, 2) void gemm_cat(
    const unsigned short* __restrict__ A1, const unsigned short* __restrict__ A2,
    const float* __restrict__ Wl, const float* __restrict__ Wr,
    const float* __restrict__ bias,
    unsigned short* __restrict__ Cb, void* __restrict__ Cf,
    const int* __restrict__ hdr, int n_nodes) {
  __shared__ float4 Wq[128 * 17];
  __shared__ float4 Fq[128 * 17];
  const int tid = threadIdx.x;
  const int tj = tid & 15;
  const int tn = tid >> 4;
  const int nb = blockIdx.x * 128;
  float acc[8][8];
  #pragma unroll
  for (int i = 0; i < 8; ++i)
    #pragma unroll
    for (int u = 0; u < 8; ++u) acc[i][u] = 0.f;

  const int NCHUNK = (K1 + K2) / 64;
  for (int c = 0; c < NCHUNK; ++c) {
    const bool first = (c * 64) < K1;
    const float* W = first ? Wl : Wr;
    const unsigned short* A = first ? A1 : A2;
    const int kb = first ? c * 64 : c * 64 - K1;
    const int Krow = first ? K1 : K2;
    __syncthreads();
    #pragma unroll
    for (int t = 0; t < 8; ++t) {
      int idx = t * 256 + tid;
      int kq = idx & 15, j = idx >> 4;
      Wq[j * 17 + kq] = *(const float4*)&W[j * Krow + kb + kq * 4];
    }
    #pragma unroll
    for (int t = 0; t < 8; ++t) {
      int idx = t * 256 + tid;
      int kq = idx & 15, nl = idx >> 4;
      int n = nb + nl;
      float4 v = make_float4(0.f, 0.f, 0.f, 0.f);
      if (n < n_nodes) {
        ushort4 us = *(const ushort4*)&A[n * Krow + kb + kq * 4];
        v = make_float4(b2f(us.x), b2f(us.y), b2f(us.z), b2f(us.w));
      }
      Fq[nl * 17 + kq] = v;
    }
    __syncthreads();
    for (int kq = 0; kq < 16; ++kq) {
      float4 w[8], f[8];
      #pragma unroll
      for (int u = 0; u < 8; ++u) w[u] = Wq[(tj + u * 16) * 17 + kq];
      #pragma unroll
      for (int i = 0; i < 8; ++i) f[i] = Fq[(tn + i * 16) * 17 + kq];
      #pragma unroll
      for (int i = 0; i < 8; ++i)
        #pragma unroll
        for (int u = 0; u < 8; ++u) {
          acc[i][u] = fmaf(f[i].x, w[u].x, acc[i][u]);
          acc[i][u] = fmaf(f[i].y, w[u].y, acc[i][u]);
          acc[i][u] = fmaf(f[i].z, w[u].z, acc[i][u]);
          acc[i][u] = fmaf(f[i].w, w[u].w, acc[i][u]);
        }
    }
  }
  const bool f32out = FINAL && (hdr[0] == 1);
  #pragma unroll
  for (int i = 0; i < 8; ++i) {
    int n = nb + tn + i * 16;
    if (n >= n_nodes) continue;
    #pragma unroll
    for (int u = 0; u < 8; ++u) {
      int j = tj + u * 16;
      float v = acc[i][u] + bias[j];
      if (RELU) v = fmaxf(v, 0.f);
      if (FINAL) {
        if (f32out) ((float*)Cf)[n * 128 + j] = v;
        else ((unsigned short*)Cf)[n * 128 + j] = f2b(v);
      } else {
        Cb[n * 128 + j] = f2b(v);
      }
    }
  }
}

// ---------- launch ----------
extern "C" void kernel_launch(void* const* d_in, const int* in_sizes, int n_in,
                              void* d_out, int out_size, void* d_ws, size_t ws_size,
                              hipStream_t stream) {
  const void* x_raw  = d_in[0];
  const int* idx_raw = (const int*)d_in[1];
  const void* W1l = d_in[2];
  const void* b1  = d_in[3];
  const void* W1r = d_in[4];
  const void* W2l = d_in[5];
  const void* b2  = d_in[6];
  const void* W2r = d_in[7];
  const int N = in_sizes[0] / 64;
  const int E = in_sizes[1] / 2;
  const int NB = (N + 2047) / 2048;

  char* ws = (char*)d_ws;
  size_t off = 0;
  auto alloc = [&](size_t bytes) {
    char* p = ws + off;
    off = (off + bytes + 511) & ~((size_t)511);
    return p;
  };
  int* hdr        = (int*)alloc(512);
  int* srcc       = (int*)alloc((size_t)E * 4);
  int* dstc       = (int*)alloc((size_t)E * 4);
  int* row_start  = (int*)alloc(((size_t)N + 1) * 4);
  int* cursor     = (int*)alloc((size_t)N * 4);
  int* cnt        = (int*)alloc((size_t)N * 4);
  int* col        = (int*)alloc((size_t)E * 4);
  float* deg_inv  = (float*)alloc((size_t)N * 4);
  int* blockSums  = (int*)alloc((size_t)NB * 4);
  int* blockOffs  = (int*)alloc((size_t)NB * 4);
  float* W1l_f    = (float*)alloc(32768);
  float* W1r_f    = (float*)alloc(32768);
  float* W2l_f    = (float*)alloc(65536);
  float* W2r_f    = (float*)alloc(65536);
  float* b1_f     = (float*)alloc(512);
  float* b2_f     = (float*)alloc(512);
  unsigned short* xc   = (unsigned short*)alloc((size_t)N * 64 * 2);
  unsigned short* agg1 = (unsigned short*)alloc((size_t)N * 64 * 2);
  unsigned short* hbuf = (unsigned short*)alloc((size_t)N * 128 * 2);
  unsigned short* agg2 = (unsigned short*)alloc((size_t)N * 128 * 2);

  detect_kernel<<<1, 64, 0, stream>>>(x_raw, idx_raw, hdr);
  hipMemsetAsync(cnt, 0, (size_t)N * 4, stream);
  convert_idx_hist_kernel<<<(E + 255) / 256, 256, 0, stream>>>(idx_raw, hdr, srcc, dstc, cnt, E);
  convert_w_kernel<<<(49408 + 255) / 256, 256, 0, stream>>>(
      W1l, W1r, W2l, W2r, b1, b2, hdr, W1l_f, W1r_f, W2l_f, W2r_f, b1_f, b2_f);
  convert_x_kernel<<<(N * 64 + 255) / 256, 256, 0, stream>>>(x_raw, hdr, xc, N * 64);
  scan_sums_kernel<<<NB, 256, 0, stream>>>(cnt, blockSums, N);
  scan_offsets_kernel<<<1, 64, 0, stream>>>(blockSums, blockOffs, NB);
  scan_emit_kernel<<<NB, 256, 0, stream>>>(cnt, blockOffs, row_start, cursor, deg_inv, N, E);
  fill_kernel<<<(E + 255) / 256, 256, 0, stream>>>(srcc, dstc, cursor, col, E);
  gather1_kernel<<<(N + 3) / 4, 256, 0, stream>>>(xc, row_start, col, deg_inv, agg1, N);
  gemm_cat<64, 64, true, false><<<(N + 127) / 128, 256, 0, stream>>>(
      agg1, xc, W1l_f, W1r_f, b1_f, hbuf, nullptr, hdr, N);
  gather2_kernel<<<(N + 3) / 4, 256, 0, stream>>>(hbuf, row_start, col, deg_inv, agg2, N);
  gemm_cat<128, 128, false, true><<<(N + 127) / 128, 256, 0, stream>>>(
      agg2, hbuf, W2l_f, W2r_f, b2_f, nullptr, d_out, hdr, N);
}

// Round 3
// 482.410 us; speedup vs baseline: 1.7457x; 1.2222x over previous
//
#include <hip/hip_runtime.h>
#include <hip/hip_bf16.h>

// ---------- helpers ----------
__device__ __forceinline__ float b2f(unsigned short u) {
  return __uint_as_float(((unsigned int)u) << 16);
}
__device__ __forceinline__ unsigned short f2b(float f) {
  unsigned int x = __float_as_uint(f);
  unsigned int r = x + 0x7FFFu + ((x >> 16) & 1u);  // RNE
  return (unsigned short)(r >> 16);
}
__device__ __forceinline__ unsigned int pack2(float lo, float hi) {
  return (unsigned int)f2b(lo) | ((unsigned int)f2b(hi) << 16);
}

typedef short bf16x8 __attribute__((ext_vector_type(8)));  // 8 bf16 = 4 VGPRs
typedef float f32x4 __attribute__((ext_vector_type(4)));

// ---------- dtype detection ----------
// hdr[0]: 0 = floats are bf16, 1 = floats are f32
// hdr[1]: 0 = edge_index int32, 1 = int64
__global__ void detect_kernel(const void* __restrict__ x_raw,
                              const void* __restrict__ idx_raw,
                              int* __restrict__ hdr) {
  int lane = threadIdx.x;  // 64 threads
  const unsigned short* xb = (const unsigned short*)x_raw;
  unsigned short u = xb[2 * lane];
  int e = (u >> 7) & 0xFF;
  bool sane = ((u & 0x7FFFu) == 0) || (e >= 107 && e <= 137);
  unsigned long long m = __ballot(sane);
  const int* ib = (const int*)idx_raw;
  int v = ib[2 * lane + 1];
  unsigned long long m2 = __ballot(v != 0);
  if (lane == 0) {
    hdr[0] = (__popcll(m) >= 32) ? 0 : 1;
    hdr[1] = (m2 == 0ull) ? 1 : 0;
  }
}

// ---------- canonicalize indices + degree histogram (fused) ----------
__global__ void convert_idx_hist_kernel(const int* __restrict__ idx_raw,
                                        const int* __restrict__ hdr,
                                        int* __restrict__ src, int* __restrict__ dst,
                                        int* __restrict__ cnt, int n_edges) {
  int e = blockIdx.x * blockDim.x + threadIdx.x;
  if (e >= n_edges) return;
  int s, d;
  if (hdr[1]) {  // int64 little-endian low words
    s = idx_raw[2 * e];
    d = idx_raw[2 * (n_edges + e)];
  } else {
    s = idx_raw[e];
    d = idx_raw[n_edges + e];
  }
  src[e] = s;
  dst[e] = d;
  atomicAdd(&cnt[d], 1);
}

// ---------- weights -> bf16, biases -> f32 ----------
__global__ void convert_w_kernel(const void* __restrict__ W1l, const void* __restrict__ W1r,
                                 const void* __restrict__ W2l, const void* __restrict__ W2r,
                                 const void* __restrict__ b1, const void* __restrict__ b2,
                                 const int* __restrict__ hdr,
                                 unsigned short* __restrict__ W1l_h, unsigned short* __restrict__ W1r_h,
                                 unsigned short* __restrict__ W2l_h, unsigned short* __restrict__ W2r_h,
                                 float* __restrict__ b1_f, float* __restrict__ b2_f) {
  int i = blockIdx.x * blockDim.x + threadIdx.x;
  const void* s; unsigned short* dh = nullptr; float* df = nullptr; int off;
  if (i < 8192)       { s = W1l; dh = W1l_h; off = i; }
  else if (i < 16384) { s = W1r; dh = W1r_h; off = i - 8192; }
  else if (i < 32768) { s = W2l; dh = W2l_h; off = i - 16384; }
  else if (i < 49152) { s = W2r; dh = W2r_h; off = i - 32768; }
  else if (i < 49280) { s = b1;  df = b1_f;  off = i - 49152; }
  else if (i < 49408) { s = b2;  df = b2_f;  off = i - 49280; }
  else return;
  float v = hdr[0] ? ((const float*)s)[off] : b2f(((const unsigned short*)s)[off]);
  if (dh) dh[off] = f2b(v);  // identity when input already bf16
  else df[off] = v;
}

__global__ void convert_x_kernel(const void* __restrict__ x_raw,
                                 const int* __restrict__ hdr,
                                 unsigned short* __restrict__ xc, int n_elems) {
  int i = blockIdx.x * blockDim.x + threadIdx.x;
  if (i >= n_elems) return;
  xc[i] = hdr[0] ? f2b(((const float*)x_raw)[i]) : ((const unsigned short*)x_raw)[i];
}

// ---------- multi-block exclusive scan of cnt -> row_start / cursor / deg_inv ----------
__global__ __launch_bounds__(256) void scan_sums_kernel(const int* __restrict__ cnt,
                                                        int* __restrict__ blockSums, int n) {
  __shared__ int ws[4];
  int tid = threadIdx.x, lane = tid & 63, wid = tid >> 6;
  int base = blockIdx.x * 2048 + tid * 8;
  int s = 0;
  #pragma unroll
  for (int t = 0; t < 8; ++t) {
    int i = base + t;
    if (i < n) s += cnt[i];
  }
  #pragma unroll
  for (int m = 1; m < 64; m <<= 1) s += __shfl_xor(s, m, 64);
  if (lane == 0) ws[wid] = s;
  __syncthreads();
  if (tid == 0) blockSums[blockIdx.x] = ws[0] + ws[1] + ws[2] + ws[3];
}

__global__ void scan_offsets_kernel(const int* __restrict__ blockSums,
                                    int* __restrict__ blockOffs, int nb) {
  int lane = threadIdx.x;  // 64
  int carry = 0;
  for (int start = 0; start < nb; start += 64) {
    int i = start + lane;
    int v = (i < nb) ? blockSums[i] : 0;
    int isc = v;
    #pragma unroll
    for (int off = 1; off < 64; off <<= 1) {
      int t = __shfl_up(isc, off, 64);
      if (lane >= off) isc += t;
    }
    if (i < nb) blockOffs[i] = carry + isc - v;
    carry += __shfl(isc, 63, 64);
  }
}

__global__ __launch_bounds__(256) void scan_emit_kernel(const int* __restrict__ cnt,
                                                        const int* __restrict__ blockOffs,
                                                        int* __restrict__ row_start,
                                                        int* __restrict__ cursor,
                                                        float* __restrict__ deg_inv,
                                                        int n, int n_edges) {
  __shared__ int ws[4];
  int tid = threadIdx.x, lane = tid & 63, wid = tid >> 6;
  int base = blockIdx.x * 2048 + tid * 8;
  int v[8];
  int s = 0;
  #pragma unroll
  for (int t = 0; t < 8; ++t) {
    int i = base + t;
    v[t] = (i < n) ? cnt[i] : 0;
    s += v[t];
  }
  int isc = s;
  #pragma unroll
  for (int off = 1; off < 64; off <<= 1) {
    int t = __shfl_up(isc, off, 64);
    if (lane >= off) isc += t;
  }
  if (lane == 63) ws[wid] = isc;
  __syncthreads();
  int wb = 0;
  #pragma unroll
  for (int w = 0; w < 4; ++w)
    if (w < wid) wb += ws[w];
  int excl = blockOffs[blockIdx.x] + wb + isc - s;
  #pragma unroll
  for (int t = 0; t < 8; ++t) {
    int i = base + t;
    if (i < n) {
      row_start[i] = excl;
      cursor[i] = excl;
      deg_inv[i] = 1.0f / (float)((v[t] > 1) ? v[t] : 1);
      excl += v[t];
    }
  }
  if (blockIdx.x == 0 && tid == 0) row_start[n] = n_edges;
}

__global__ void fill_kernel(const int* __restrict__ src, const int* __restrict__ dst,
                            int* __restrict__ cursor, int* __restrict__ col, int n_edges) {
  int e = blockIdx.x * blockDim.x + threadIdx.x;
  if (e >= n_edges) return;
  int pos = atomicAdd(&cursor[dst[e]], 1);
  col[pos] = src[e];
}

// ---------- vectorized mean-aggregation gathers ----------
__global__ __launch_bounds__(256) void gather1_kernel(
    const unsigned short* __restrict__ xc, const int* __restrict__ row_start,
    const int* __restrict__ col, const float* __restrict__ deg_inv,
    unsigned short* __restrict__ agg1, int n_nodes) {
  int lane = threadIdx.x & 63;
  int n = blockIdx.x * 4 + (threadIdx.x >> 6);
  if (n >= n_nodes) return;
  int rg = lane >> 3, fq = lane & 7;
  int beg = row_start[n], end = row_start[n + 1];
  float a[8];
  #pragma unroll
  for (int t = 0; t < 8; ++t) a[t] = 0.f;
  int i = beg;
  for (; i + 15 < end; i += 16) {
    int s0 = col[i + rg], s1 = col[i + 8 + rg];
    uint4 p = *(const uint4*)(xc + (size_t)s0 * 64 + fq * 8);
    uint4 q = *(const uint4*)(xc + (size_t)s1 * 64 + fq * 8);
    a[0] += b2f(p.x & 0xFFFF); a[1] += b2f(p.x >> 16);
    a[2] += b2f(p.y & 0xFFFF); a[3] += b2f(p.y >> 16);
    a[4] += b2f(p.z & 0xFFFF); a[5] += b2f(p.z >> 16);
    a[6] += b2f(p.w & 0xFFFF); a[7] += b2f(p.w >> 16);
    a[0] += b2f(q.x & 0xFFFF); a[1] += b2f(q.x >> 16);
    a[2] += b2f(q.y & 0xFFFF); a[3] += b2f(q.y >> 16);
    a[4] += b2f(q.z & 0xFFFF); a[5] += b2f(q.z >> 16);
    a[6] += b2f(q.w & 0xFFFF); a[7] += b2f(q.w >> 16);
  }
  for (; i < end; i += 8) {
    if (i + rg < end) {
      int s0 = col[i + rg];
      uint4 p = *(const uint4*)(xc + (size_t)s0 * 64 + fq * 8);
      a[0] += b2f(p.x & 0xFFFF); a[1] += b2f(p.x >> 16);
      a[2] += b2f(p.y & 0xFFFF); a[3] += b2f(p.y >> 16);
      a[4] += b2f(p.z & 0xFFFF); a[5] += b2f(p.z >> 16);
      a[6] += b2f(p.w & 0xFFFF); a[7] += b2f(p.w >> 16);
    }
  }
  #pragma unroll
  for (int m = 8; m < 64; m <<= 1)
    #pragma unroll
    for (int t = 0; t < 8; ++t) a[t] += __shfl_xor(a[t], m, 64);
  if (rg == 0) {
    float di = deg_inv[n];
    uint4 o;
    o.x = pack2(a[0] * di, a[1] * di);
    o.y = pack2(a[2] * di, a[3] * di);
    o.z = pack2(a[4] * di, a[5] * di);
    o.w = pack2(a[6] * di, a[7] * di);
    *(uint4*)(agg1 + (size_t)n * 64 + fq * 8) = o;
  }
}

__global__ __launch_bounds__(256) void gather2_kernel(
    const unsigned short* __restrict__ h, const int* __restrict__ row_start,
    const int* __restrict__ col, const float* __restrict__ deg_inv,
    unsigned short* __restrict__ agg2, int n_nodes) {
  int lane = threadIdx.x & 63;
  int n = blockIdx.x * 4 + (threadIdx.x >> 6);
  if (n >= n_nodes) return;
  int rg = lane >> 4, fq = lane & 15;
  int beg = row_start[n], end = row_start[n + 1];
  float a[8];
  #pragma unroll
  for (int t = 0; t < 8; ++t) a[t] = 0.f;
  int i = beg;
  for (; i + 7 < end; i += 8) {
    int s0 = col[i + rg], s1 = col[i + 4 + rg];
    uint4 p = *(const uint4*)(h + (size_t)s0 * 128 + fq * 8);
    uint4 q = *(const uint4*)(h + (size_t)s1 * 128 + fq * 8);
    a[0] += b2f(p.x & 0xFFFF); a[1] += b2f(p.x >> 16);
    a[2] += b2f(p.y & 0xFFFF); a[3] += b2f(p.y >> 16);
    a[4] += b2f(p.z & 0xFFFF); a[5] += b2f(p.z >> 16);
    a[6] += b2f(p.w & 0xFFFF); a[7] += b2f(p.w >> 16);
    a[0] += b2f(q.x & 0xFFFF); a[1] += b2f(q.x >> 16);
    a[2] += b2f(q.y & 0xFFFF); a[3] += b2f(q.y >> 16);
    a[4] += b2f(q.z & 0xFFFF); a[5] += b2f(q.z >> 16);
    a[6] += b2f(q.w & 0xFFFF); a[7] += b2f(q.w >> 16);
  }
  for (; i < end; i += 4) {
    if (i + rg < end) {
      int s0 = col[i + rg];
      uint4 p = *(const uint4*)(h + (size_t)s0 * 128 + fq * 8);
      a[0] += b2f(p.x & 0xFFFF); a[1] += b2f(p.x >> 16);
      a[2] += b2f(p.y & 0xFFFF); a[3] += b2f(p.y >> 16);
      a[4] += b2f(p.z & 0xFFFF); a[5] += b2f(p.z >> 16);
      a[6] += b2f(p.w & 0xFFFF); a[7] += b2f(p.w >> 16);
    }
  }
  #pragma unroll
  for (int m = 16; m < 64; m <<= 1)
    #pragma unroll
    for (int t = 0; t < 8; ++t) a[t] += __shfl_xor(a[t], m, 64);
  if (rg == 0) {
    float di = deg_inv[n];
    uint4 o;
    o.x = pack2(a[0] * di, a[1] * di);
    o.y = pack2(a[2] * di, a[3] * di);
    o.z = pack2(a[4] * di, a[5] * di);
    o.w = pack2(a[6] * di, a[7] * di);
    *(uint4*)(agg2 + (size_t)n * 128 + fq * 8) = o;
  }
}

// ---------- MFMA concat-GEMM: C = act([A1|A2] @ [Wl|Wr]^T + b) ----------
// A1,A2 bf16 [N,K*] K-major; Wl,Wr bf16 [128,K*] K-major (so B=W^T fragments
// are contiguous-k per lane). Block: 128 nodes x 128 j, 4 waves, each wave
// 32 nodes x 128 j = 2x8 MFMA tiles of 16x16x32. No LDS, no barriers.
// A-frag: lane holds A[m=lane&15][k=quad*8+j]; B-frag: W[j=lane&15][k=quad*8+jj];
// C/D: col=lane&15 (j), row=quad*4+reg (m). [verified m89/m91]
template <int K1, int K2, bool RELU, bool FINAL>
__global__ __launch_bounds__(256, 4) void gemm_mfma(
    const unsigned short* __restrict__ A1, const unsigned short* __restrict__ A2,
    const unsigned short* __restrict__ Wl, const unsigned short* __restrict__ Wr,
    const float* __restrict__ bias,
    unsigned short* __restrict__ Cb, void* __restrict__ Cf,
    const int* __restrict__ hdr, int n_nodes) {
  const int tid = threadIdx.x;
  const int wave = tid >> 6, lane = tid & 63;
  const int m16 = lane & 15, quad = lane >> 4;
  const int nb = blockIdx.x * 128 + wave * 32;
  int row0 = nb + m16;      if (row0 >= n_nodes) row0 = n_nodes - 1;
  int row1 = nb + 16 + m16; if (row1 >= n_nodes) row1 = n_nodes - 1;

  f32x4 acc[2][8];
  #pragma unroll
  for (int mi = 0; mi < 2; ++mi)
    #pragma unroll
    for (int ji = 0; ji < 8; ++ji) acc[mi][ji] = (f32x4){0.f, 0.f, 0.f, 0.f};

  constexpr int NSTEP = (K1 + K2) / 32;
  #pragma unroll
  for (int c = 0; c < NSTEP; ++c) {
    const bool first = (c * 32) < K1;
    const unsigned short* A = first ? A1 : A2;
    const unsigned short* W = first ? Wl : Wr;
    const int kb = first ? c * 32 : c * 32 - K1;
    const int Krow = first ? K1 : K2;
    const int ko = kb + quad * 8;
    bf16x8 a0 = *(const bf16x8*)(A + (size_t)row0 * Krow + ko);
    bf16x8 a1 = *(const bf16x8*)(A + (size_t)row1 * Krow + ko);
    bf16x8 w[8];
    #pragma unroll
    for (int ji = 0; ji < 8; ++ji)
      w[ji] = *(const bf16x8*)(W + (size_t)(ji * 16 + m16) * Krow + ko);
    #pragma unroll
    for (int ji = 0; ji < 8; ++ji) {
      acc[0][ji] = __builtin_amdgcn_mfma_f32_16x16x32_bf16(a0, w[ji], acc[0][ji], 0, 0, 0);
      acc[1][ji] = __builtin_amdgcn_mfma_f32_16x16x32_bf16(a1, w[ji], acc[1][ji], 0, 0, 0);
    }
  }

  const bool f32out = FINAL && (hdr[0] == 1);
  #pragma unroll
  for (int ji = 0; ji < 8; ++ji) {
    int j = ji * 16 + m16;
    float bj = bias[j];
    #pragma unroll
    for (int mi = 0; mi < 2; ++mi) {
      #pragma unroll
      for (int r = 0; r < 4; ++r) {
        int n = nb + mi * 16 + quad * 4 + r;
        if (n >= n_nodes) continue;
        float v = acc[mi][ji][r] + bj;
        if (RELU) v = fmaxf(v, 0.f);
        if (FINAL) {
          if (f32out) ((float*)Cf)[(size_t)n * 128 + j] = v;
          else ((unsigned short*)Cf)[(size_t)n * 128 + j] = f2b(v);
        } else {
          Cb[(size_t)n * 128 + j] = f2b(v);
        }
      }
    }
  }
}

// ---------- launch ----------
extern "C" void kernel_launch(void* const* d_in, const int* in_sizes, int n_in,
                              void* d_out, int out_size, void* d_ws, size_t ws_size,
                              hipStream_t stream) {
  const void* x_raw  = d_in[0];
  const int* idx_raw = (const int*)d_in[1];
  const void* W1l = d_in[2];
  const void* b1  = d_in[3];
  const void* W1r = d_in[4];
  const void* W2l = d_in[5];
  const void* b2  = d_in[6];
  const void* W2r = d_in[7];
  const int N = in_sizes[0] / 64;
  const int E = in_sizes[1] / 2;
  const int NB = (N + 2047) / 2048;

  char* ws = (char*)d_ws;
  size_t off = 0;
  auto alloc = [&](size_t bytes) {
    char* p = ws + off;
    off = (off + bytes + 511) & ~((size_t)511);
    return p;
  };
  int* hdr        = (int*)alloc(512);
  int* srcc       = (int*)alloc((size_t)E * 4);
  int* dstc       = (int*)alloc((size_t)E * 4);
  int* row_start  = (int*)alloc(((size_t)N + 1) * 4);
  int* cursor     = (int*)alloc((size_t)N * 4);
  int* cnt        = (int*)alloc((size_t)N * 4);
  int* col        = (int*)alloc((size_t)E * 4);
  float* deg_inv  = (float*)alloc((size_t)N * 4);
  int* blockSums  = (int*)alloc((size_t)NB * 4);
  int* blockOffs  = (int*)alloc((size_t)NB * 4);
  unsigned short* W1l_h = (unsigned short*)alloc(16384);
  unsigned short* W1r_h = (unsigned short*)alloc(16384);
  unsigned short* W2l_h = (unsigned short*)alloc(32768);
  unsigned short* W2r_h = (unsigned short*)alloc(32768);
  float* b1_f     = (float*)alloc(512);
  float* b2_f     = (float*)alloc(512);
  unsigned short* xc   = (unsigned short*)alloc((size_t)N * 64 * 2);
  unsigned short* agg1 = (unsigned short*)alloc((size_t)N * 64 * 2);
  unsigned short* hbuf = (unsigned short*)alloc((size_t)N * 128 * 2);
  unsigned short* agg2 = (unsigned short*)alloc((size_t)N * 128 * 2);

  detect_kernel<<<1, 64, 0, stream>>>(x_raw, idx_raw, hdr);
  hipMemsetAsync(cnt, 0, (size_t)N * 4, stream);
  convert_idx_hist_kernel<<<(E + 255) / 256, 256, 0, stream>>>(idx_raw, hdr, srcc, dstc, cnt, E);
  convert_w_kernel<<<(49408 + 255) / 256, 256, 0, stream>>>(
      W1l, W1r, W2l, W2r, b1, b2, hdr, W1l_h, W1r_h, W2l_h, W2r_h, b1_f, b2_f);
  convert_x_kernel<<<(N * 64 + 255) / 256, 256, 0, stream>>>(x_raw, hdr, xc, N * 64);
  scan_sums_kernel<<<NB, 256, 0, stream>>>(cnt, blockSums, N);
  scan_offsets_kernel<<<1, 64, 0, stream>>>(blockSums, blockOffs, NB);
  scan_emit_kernel<<<NB, 256, 0, stream>>>(cnt, blockOffs, row_start, cursor, deg_inv, N, E);
  fill_kernel<<<(E + 255) / 256, 256, 0, stream>>>(srcc, dstc, cursor, col, E);
  gather1_kernel<<<(N + 3) / 4, 256, 0, stream>>>(xc, row_start, col, deg_inv, agg1, N);
  gemm_mfma<64, 64, true, false><<<(N + 127) / 128, 256, 0, stream>>>(
      agg1, xc, W1l_h, W1r_h, b1_f, hbuf, nullptr, hdr, N);
  gather2_kernel<<<(N + 3) / 4, 256, 0, stream>>>(hbuf, row_start, col, deg_inv, agg2, N);
  gemm_mfma<128, 128, false, true><<<(N + 127) / 128, 256, 0, stream>>>(
      agg2, hbuf, W2l_h, W2r_h, b2_f, nullptr, d_out, hdr, N);
}

// Round 4
// 395.861 us; speedup vs baseline: 2.1274x; 1.2186x over previous
//
#include <hip/hip_runtime.h>
#include <hip/hip_bf16.h>

// ---------- helpers ----------
__device__ __forceinline__ float b2f(unsigned short u) {
  return __uint_as_float(((unsigned int)u) << 16);
}
__device__ __forceinline__ unsigned short f2b(float f) {
  unsigned int x = __float_as_uint(f);
  unsigned int r = x + 0x7FFFu + ((x >> 16) & 1u);  // RNE
  return (unsigned short)(r >> 16);
}
__device__ __forceinline__ unsigned int pack2(float lo, float hi) {
  return (unsigned int)f2b(lo) | ((unsigned int)f2b(hi) << 16);
}

typedef short bf16x8 __attribute__((ext_vector_type(8)));  // 8 bf16 = 4 VGPRs
typedef float f32x4 __attribute__((ext_vector_type(4)));

// ---------- dtype detection ----------
// hdr[0]: 0 = floats are bf16, 1 = floats are f32
// hdr[1]: 0 = edge_index int32, 1 = int64
__global__ void detect_kernel(const void* __restrict__ x_raw,
                              const void* __restrict__ idx_raw,
                              int* __restrict__ hdr) {
  int lane = threadIdx.x;  // 64 threads
  const unsigned short* xb = (const unsigned short*)x_raw;
  unsigned short u = xb[2 * lane];
  int e = (u >> 7) & 0xFF;
  bool sane = ((u & 0x7FFFu) == 0) || (e >= 107 && e <= 137);
  unsigned long long m = __ballot(sane);
  const int* ib = (const int*)idx_raw;
  int v = ib[2 * lane + 1];
  unsigned long long m2 = __ballot(v != 0);
  if (lane == 0) {
    hdr[0] = (__popcll(m) >= 32) ? 0 : 1;
    hdr[1] = (m2 == 0ull) ? 1 : 0;
  }
}

// ---------- canonicalize indices + degree histogram + per-edge rank ----------
// rank[e] = old count -> fill needs no second atomic pass.
__global__ void convert_idx_hist_kernel(const int* __restrict__ idx_raw,
                                        const int* __restrict__ hdr,
                                        int* __restrict__ src, int* __restrict__ dst,
                                        int* __restrict__ rank,
                                        int* __restrict__ cnt, int n_edges) {
  int e = blockIdx.x * blockDim.x + threadIdx.x;
  if (e >= n_edges) return;
  int s, d;
  if (hdr[1]) {  // int64 little-endian low words
    s = idx_raw[2 * e];
    d = idx_raw[2 * (n_edges + e)];
  } else {
    s = idx_raw[e];
    d = idx_raw[n_edges + e];
  }
  src[e] = s;
  dst[e] = d;
  rank[e] = atomicAdd(&cnt[d], 1);
}

// ---------- weights -> bf16, biases -> f32 ----------
__global__ void convert_w_kernel(const void* __restrict__ W1l, const void* __restrict__ W1r,
                                 const void* __restrict__ W2l, const void* __restrict__ W2r,
                                 const void* __restrict__ b1, const void* __restrict__ b2,
                                 const int* __restrict__ hdr,
                                 unsigned short* __restrict__ W1l_h, unsigned short* __restrict__ W1r_h,
                                 unsigned short* __restrict__ W2l_h, unsigned short* __restrict__ W2r_h,
                                 float* __restrict__ b1_f, float* __restrict__ b2_f) {
  int i = blockIdx.x * blockDim.x + threadIdx.x;
  const void* s; unsigned short* dh = nullptr; float* df = nullptr; int off;
  if (i < 8192)       { s = W1l; dh = W1l_h; off = i; }
  else if (i < 16384) { s = W1r; dh = W1r_h; off = i - 8192; }
  else if (i < 32768) { s = W2l; dh = W2l_h; off = i - 16384; }
  else if (i < 49152) { s = W2r; dh = W2r_h; off = i - 32768; }
  else if (i < 49280) { s = b1;  df = b1_f;  off = i - 49152; }
  else if (i < 49408) { s = b2;  df = b2_f;  off = i - 49280; }
  else return;
  float v = hdr[0] ? ((const float*)s)[off] : b2f(((const unsigned short*)s)[off]);
  if (dh) dh[off] = f2b(v);  // identity when input already bf16
  else df[off] = v;
}

__global__ void convert_x_kernel(const void* __restrict__ x_raw,
                                 const int* __restrict__ hdr,
                                 unsigned short* __restrict__ xc, int n_elems) {
  int i = blockIdx.x * blockDim.x + threadIdx.x;
  if (i >= n_elems) return;
  xc[i] = hdr[0] ? f2b(((const float*)x_raw)[i]) : ((const unsigned short*)x_raw)[i];
}

// ---------- multi-block exclusive scan of cnt -> row_start / deg_inv ----------
__global__ __launch_bounds__(256) void scan_sums_kernel(const int* __restrict__ cnt,
                                                        int* __restrict__ blockSums, int n) {
  __shared__ int ws[4];
  int tid = threadIdx.x, lane = tid & 63, wid = tid >> 6;
  int base = blockIdx.x * 2048 + tid * 8;
  int s = 0;
  #pragma unroll
  for (int t = 0; t < 8; ++t) {
    int i = base + t;
    if (i < n) s += cnt[i];
  }
  #pragma unroll
  for (int m = 1; m < 64; m <<= 1) s += __shfl_xor(s, m, 64);
  if (lane == 0) ws[wid] = s;
  __syncthreads();
  if (tid == 0) blockSums[blockIdx.x] = ws[0] + ws[1] + ws[2] + ws[3];
}

__global__ void scan_offsets_kernel(const int* __restrict__ blockSums,
                                    int* __restrict__ blockOffs, int nb) {
  int lane = threadIdx.x;  // 64
  int carry = 0;
  for (int start = 0; start < nb; start += 64) {
    int i = start + lane;
    int v = (i < nb) ? blockSums[i] : 0;
    int isc = v;
    #pragma unroll
    for (int off = 1; off < 64; off <<= 1) {
      int t = __shfl_up(isc, off, 64);
      if (lane >= off) isc += t;
    }
    if (i < nb) blockOffs[i] = carry + isc - v;
    carry += __shfl(isc, 63, 64);
  }
}

__global__ __launch_bounds__(256) void scan_emit_kernel(const int* __restrict__ cnt,
                                                        const int* __restrict__ blockOffs,
                                                        int* __restrict__ row_start,
                                                        float* __restrict__ deg_inv,
                                                        int n, int n_edges) {
  __shared__ int ws[4];
  int tid = threadIdx.x, lane = tid & 63, wid = tid >> 6;
  int base = blockIdx.x * 2048 + tid * 8;
  int v[8];
  int s = 0;
  #pragma unroll
  for (int t = 0; t < 8; ++t) {
    int i = base + t;
    v[t] = (i < n) ? cnt[i] : 0;
    s += v[t];
  }
  int isc = s;
  #pragma unroll
  for (int off = 1; off < 64; off <<= 1) {
    int t = __shfl_up(isc, off, 64);
    if (lane >= off) isc += t;
  }
  if (lane == 63) ws[wid] = isc;
  __syncthreads();
  int wb = 0;
  #pragma unroll
  for (int w = 0; w < 4; ++w)
    if (w < wid) wb += ws[w];
  int excl = blockOffs[blockIdx.x] + wb + isc - s;
  #pragma unroll
  for (int t = 0; t < 8; ++t) {
    int i = base + t;
    if (i < n) {
      row_start[i] = excl;
      deg_inv[i] = 1.0f / (float)((v[t] > 1) ? v[t] : 1);
      excl += v[t];
    }
  }
  if (blockIdx.x == 0 && tid == 0) row_start[n] = n_edges;
}

// ---------- CSR bucket fill: atomic-free, XCD-partitioned by dst range ----------
// All writes to one col cache line (one node's ~64B segment) come from the
// same dst partition; blockIdx&7 -> XCD round-robin keeps a partition's
// writes in one L2 so lines are fully assembled before writeback (R3 showed
// 16x write amplification without this: WRITE_SIZE = E*64B).
__global__ __launch_bounds__(256) void fill_kernel(
    const int* __restrict__ src, const int* __restrict__ dst,
    const int* __restrict__ rank, const int* __restrict__ row_start,
    int* __restrict__ col, int n_edges, int n_nodes) {
  int part = blockIdx.x & 7;
  int e = (blockIdx.x >> 3) * 256 + threadIdx.x;
  if (e >= n_edges) return;
  int d = dst[e];
  int p = (int)(((long long)d * 8) / n_nodes);
  if (p != part) return;
  col[row_start[d] + rank[e]] = src[e];
}

// ---------- vectorized mean-aggregation gathers ----------
__global__ __launch_bounds__(256) void gather1_kernel(
    const unsigned short* __restrict__ xc, const int* __restrict__ row_start,
    const int* __restrict__ col, const float* __restrict__ deg_inv,
    unsigned short* __restrict__ agg1, int n_nodes) {
  int lane = threadIdx.x & 63;
  int n = blockIdx.x * 4 + (threadIdx.x >> 6);
  if (n >= n_nodes) return;
  int rg = lane >> 3, fq = lane & 7;
  int beg = row_start[n], end = row_start[n + 1];
  float a[8];
  #pragma unroll
  for (int t = 0; t < 8; ++t) a[t] = 0.f;
  int i = beg;
  for (; i + 15 < end; i += 16) {
    int s0 = col[i + rg], s1 = col[i + 8 + rg];
    uint4 p = *(const uint4*)(xc + (size_t)s0 * 64 + fq * 8);
    uint4 q = *(const uint4*)(xc + (size_t)s1 * 64 + fq * 8);
    a[0] += b2f(p.x & 0xFFFF); a[1] += b2f(p.x >> 16);
    a[2] += b2f(p.y & 0xFFFF); a[3] += b2f(p.y >> 16);
    a[4] += b2f(p.z & 0xFFFF); a[5] += b2f(p.z >> 16);
    a[6] += b2f(p.w & 0xFFFF); a[7] += b2f(p.w >> 16);
    a[0] += b2f(q.x & 0xFFFF); a[1] += b2f(q.x >> 16);
    a[2] += b2f(q.y & 0xFFFF); a[3] += b2f(q.y >> 16);
    a[4] += b2f(q.z & 0xFFFF); a[5] += b2f(q.z >> 16);
    a[6] += b2f(q.w & 0xFFFF); a[7] += b2f(q.w >> 16);
  }
  for (; i < end; i += 8) {
    if (i + rg < end) {
      int s0 = col[i + rg];
      uint4 p = *(const uint4*)(xc + (size_t)s0 * 64 + fq * 8);
      a[0] += b2f(p.x & 0xFFFF); a[1] += b2f(p.x >> 16);
      a[2] += b2f(p.y & 0xFFFF); a[3] += b2f(p.y >> 16);
      a[4] += b2f(p.z & 0xFFFF); a[5] += b2f(p.z >> 16);
      a[6] += b2f(p.w & 0xFFFF); a[7] += b2f(p.w >> 16);
    }
  }
  #pragma unroll
  for (int m = 8; m < 64; m <<= 1)
    #pragma unroll
    for (int t = 0; t < 8; ++t) a[t] += __shfl_xor(a[t], m, 64);
  if (rg == 0) {
    float di = deg_inv[n];
    uint4 o;
    o.x = pack2(a[0] * di, a[1] * di);
    o.y = pack2(a[2] * di, a[3] * di);
    o.z = pack2(a[4] * di, a[5] * di);
    o.w = pack2(a[6] * di, a[7] * di);
    *(uint4*)(agg1 + (size_t)n * 64 + fq * 8) = o;
  }
}

__global__ __launch_bounds__(256) void gather2_kernel(
    const unsigned short* __restrict__ h, const int* __restrict__ row_start,
    const int* __restrict__ col, const float* __restrict__ deg_inv,
    unsigned short* __restrict__ agg2, int n_nodes) {
  int lane = threadIdx.x & 63;
  int n = blockIdx.x * 4 + (threadIdx.x >> 6);
  if (n >= n_nodes) return;
  int rg = lane >> 4, fq = lane & 15;
  int beg = row_start[n], end = row_start[n + 1];
  float a[8];
  #pragma unroll
  for (int t = 0; t < 8; ++t) a[t] = 0.f;
  int i = beg;
  for (; i + 7 < end; i += 8) {
    int s0 = col[i + rg], s1 = col[i + 4 + rg];
    uint4 p = *(const uint4*)(h + (size_t)s0 * 128 + fq * 8);
    uint4 q = *(const uint4*)(h + (size_t)s1 * 128 + fq * 8);
    a[0] += b2f(p.x & 0xFFFF); a[1] += b2f(p.x >> 16);
    a[2] += b2f(p.y & 0xFFFF); a[3] += b2f(p.y >> 16);
    a[4] += b2f(p.z & 0xFFFF); a[5] += b2f(p.z >> 16);
    a[6] += b2f(p.w & 0xFFFF); a[7] += b2f(p.w >> 16);
    a[0] += b2f(q.x & 0xFFFF); a[1] += b2f(q.x >> 16);
    a[2] += b2f(q.y & 0xFFFF); a[3] += b2f(q.y >> 16);
    a[4] += b2f(q.z & 0xFFFF); a[5] += b2f(q.z >> 16);
    a[6] += b2f(q.w & 0xFFFF); a[7] += b2f(q.w >> 16);
  }
  for (; i < end; i += 4) {
    if (i + rg < end) {
      int s0 = col[i + rg];
      uint4 p = *(const uint4*)(h + (size_t)s0 * 128 + fq * 8);
      a[0] += b2f(p.x & 0xFFFF); a[1] += b2f(p.x >> 16);
      a[2] += b2f(p.y & 0xFFFF); a[3] += b2f(p.y >> 16);
      a[4] += b2f(p.z & 0xFFFF); a[5] += b2f(p.z >> 16);
      a[6] += b2f(p.w & 0xFFFF); a[7] += b2f(p.w >> 16);
    }
  }
  #pragma unroll
  for (int m = 16; m < 64; m <<= 1)
    #pragma unroll
    for (int t = 0; t < 8; ++t) a[t] += __shfl_xor(a[t], m, 64);
  if (rg == 0) {
    float di = deg_inv[n];
    uint4 o;
    o.x = pack2(a[0] * di, a[1] * di);
    o.y = pack2(a[2] * di, a[3] * di);
    o.z = pack2(a[4] * di, a[5] * di);
    o.w = pack2(a[6] * di, a[7] * di);
    *(uint4*)(agg2 + (size_t)n * 128 + fq * 8) = o;
  }
}

// ---------- MFMA concat-GEMM: C = act([A1|A2] @ [Wl|Wr]^T + b) ----------
template <int K1, int K2, bool RELU, bool FINAL>
__global__ __launch_bounds__(256, 4) void gemm_mfma(
    const unsigned short* __restrict__ A1, const unsigned short* __restrict__ A2,
    const unsigned short* __restrict__ Wl, const unsigned short* __restrict__ Wr,
    const float* __restrict__ bias,
    unsigned short* __restrict__ Cb, void* __restrict__ Cf,
    const int* __restrict__ hdr, int n_nodes) {
  const int tid = threadIdx.x;
  const int wave = tid >> 6, lane = tid & 63;
  const int m16 = lane & 15, quad = lane >> 4;
  const int nb = blockIdx.x * 128 + wave * 32;
  int row0 = nb + m16;      if (row0 >= n_nodes) row0 = n_nodes - 1;
  int row1 = nb + 16 + m16; if (row1 >= n_nodes) row1 = n_nodes - 1;

  f32x4 acc[2][8];
  #pragma unroll
  for (int mi = 0; mi < 2; ++mi)
    #pragma unroll
    for (int ji = 0; ji < 8; ++ji) acc[mi][ji] = (f32x4){0.f, 0.f, 0.f, 0.f};

  constexpr int NSTEP = (K1 + K2) / 32;
  #pragma unroll
  for (int c = 0; c < NSTEP; ++c) {
    const bool first = (c * 32) < K1;
    const unsigned short* A = first ? A1 : A2;
    const unsigned short* W = first ? Wl : Wr;
    const int kb = first ? c * 32 : c * 32 - K1;
    const int Krow = first ? K1 : K2;
    const int ko = kb + quad * 8;
    bf16x8 a0 = *(const bf16x8*)(A + (size_t)row0 * Krow + ko);
    bf16x8 a1 = *(const bf16x8*)(A + (size_t)row1 * Krow + ko);
    bf16x8 w[8];
    #pragma unroll
    for (int ji = 0; ji < 8; ++ji)
      w[ji] = *(const bf16x8*)(W + (size_t)(ji * 16 + m16) * Krow + ko);
    #pragma unroll
    for (int ji = 0; ji < 8; ++ji) {
      acc[0][ji] = __builtin_amdgcn_mfma_f32_16x16x32_bf16(a0, w[ji], acc[0][ji], 0, 0, 0);
      acc[1][ji] = __builtin_amdgcn_mfma_f32_16x16x32_bf16(a1, w[ji], acc[1][ji], 0, 0, 0);
    }
  }

  const bool f32out = FINAL && (hdr[0] == 1);
  #pragma unroll
  for (int ji = 0; ji < 8; ++ji) {
    int j = ji * 16 + m16;
    float bj = bias[j];
    #pragma unroll
    for (int mi = 0; mi < 2; ++mi) {
      #pragma unroll
      for (int r = 0; r < 4; ++r) {
        int n = nb + mi * 16 + quad * 4 + r;
        if (n >= n_nodes) continue;
        float v = acc[mi][ji][r] + bj;
        if (RELU) v = fmaxf(v, 0.f);
        if (FINAL) {
          if (f32out) ((float*)Cf)[(size_t)n * 128 + j] = v;
          else ((unsigned short*)Cf)[(size_t)n * 128 + j] = f2b(v);
        } else {
          Cb[(size_t)n * 128 + j] = f2b(v);
        }
      }
    }
  }
}

// ---------- launch ----------
extern "C" void kernel_launch(void* const* d_in, const int* in_sizes, int n_in,
                              void* d_out, int out_size, void* d_ws, size_t ws_size,
                              hipStream_t stream) {
  const void* x_raw  = d_in[0];
  const int* idx_raw = (const int*)d_in[1];
  const void* W1l = d_in[2];
  const void* b1  = d_in[3];
  const void* W1r = d_in[4];
  const void* W2l = d_in[5];
  const void* b2  = d_in[6];
  const void* W2r = d_in[7];
  const int N = in_sizes[0] / 64;
  const int E = in_sizes[1] / 2;
  const int NB = (N + 2047) / 2048;

  char* ws = (char*)d_ws;
  size_t off = 0;
  auto alloc = [&](size_t bytes) {
    char* p = ws + off;
    off = (off + bytes + 511) & ~((size_t)511);
    return p;
  };
  int* hdr        = (int*)alloc(512);
  int* srcc       = (int*)alloc((size_t)E * 4);
  int* dstc       = (int*)alloc((size_t)E * 4);
  int* rankb      = (int*)alloc((size_t)E * 4);
  int* row_start  = (int*)alloc(((size_t)N + 1) * 4);
  int* cnt        = (int*)alloc((size_t)N * 4);
  int* col        = (int*)alloc((size_t)E * 4);
  float* deg_inv  = (float*)alloc((size_t)N * 4);
  int* blockSums  = (int*)alloc((size_t)NB * 4);
  int* blockOffs  = (int*)alloc((size_t)NB * 4);
  unsigned short* W1l_h = (unsigned short*)alloc(16384);
  unsigned short* W1r_h = (unsigned short*)alloc(16384);
  unsigned short* W2l_h = (unsigned short*)alloc(32768);
  unsigned short* W2r_h = (unsigned short*)alloc(32768);
  float* b1_f     = (float*)alloc(512);
  float* b2_f     = (float*)alloc(512);
  unsigned short* xc   = (unsigned short*)alloc((size_t)N * 64 * 2);
  unsigned short* agg1 = (unsigned short*)alloc((size_t)N * 64 * 2);
  unsigned short* hbuf = (unsigned short*)alloc((size_t)N * 128 * 2);
  unsigned short* agg2 = (unsigned short*)alloc((size_t)N * 128 * 2);

  detect_kernel<<<1, 64, 0, stream>>>(x_raw, idx_raw, hdr);
  hipMemsetAsync(cnt, 0, (size_t)N * 4, stream);
  convert_idx_hist_kernel<<<(E + 255) / 256, 256, 0, stream>>>(idx_raw, hdr, srcc, dstc, rankb, cnt, E);
  convert_w_kernel<<<(49408 + 255) / 256, 256, 0, stream>>>(
      W1l, W1r, W2l, W2r, b1, b2, hdr, W1l_h, W1r_h, W2l_h, W2r_h, b1_f, b2_f);
  convert_x_kernel<<<(N * 64 + 255) / 256, 256, 0, stream>>>(x_raw, hdr, xc, N * 64);
  scan_sums_kernel<<<NB, 256, 0, stream>>>(cnt, blockSums, N);
  scan_offsets_kernel<<<1, 64, 0, stream>>>(blockSums, blockOffs, NB);
  scan_emit_kernel<<<NB, 256, 0, stream>>>(cnt, blockOffs, row_start, deg_inv, N, E);
  fill_kernel<<<8 * ((E + 255) / 256), 256, 0, stream>>>(srcc, dstc, rankb, row_start, col, E, N);
  gather1_kernel<<<(N + 3) / 4, 256, 0, stream>>>(xc, row_start, col, deg_inv, agg1, N);
  gemm_mfma<64, 64, true, false><<<(N + 127) / 128, 256, 0, stream>>>(
      agg1, xc, W1l_h, W1r_h, b1_f, hbuf, nullptr, hdr, N);
  gather2_kernel<<<(N + 3) / 4, 256, 0, stream>>>(hbuf, row_start, col, deg_inv, agg2, N);
  gemm_mfma<128, 128, false, true><<<(N + 127) / 128, 256, 0, stream>>>(
      agg2, hbuf, W2l_h, W2r_h, b2_f, nullptr, d_out, hdr, N);
}

// Round 5
// 338.497 us; speedup vs baseline: 2.4879x; 1.1695x over previous
//
#include <hip/hip_runtime.h>
#include <hip/hip_bf16.h>

// ---------- helpers ----------
__device__ __forceinline__ float b2f(unsigned short u) {
  return __uint_as_float(((unsigned int)u) << 16);
}
__device__ __forceinline__ unsigned short f2b(float f) {
  unsigned int x = __float_as_uint(f);
  unsigned int r = x + 0x7FFFu + ((x >> 16) & 1u);  // RNE
  return (unsigned short)(r >> 16);
}
__device__ __forceinline__ unsigned int pack2(float lo, float hi) {
  return (unsigned int)f2b(lo) | ((unsigned int)f2b(hi) << 16);
}

typedef short bf16x8 __attribute__((ext_vector_type(8)));  // 8 bf16 = 4 VGPRs
typedef float f32x4 __attribute__((ext_vector_type(4)));

#define CHUNK 8192          // edges per P1/P3 block
#define NBUCKP 1024         // padded bucket count (bucket = dst >> 7, N <= 131072)

// ---------- dtype detection ----------
// hdr[0]: 0 = floats are bf16, 1 = floats are f32
// hdr[1]: 0 = edge_index int32, 1 = int64
__global__ void detect_kernel(const void* __restrict__ x_raw,
                              const void* __restrict__ idx_raw,
                              int* __restrict__ hdr) {
  int lane = threadIdx.x;  // 64 threads
  const unsigned short* xb = (const unsigned short*)x_raw;
  unsigned short u = xb[2 * lane];
  int e = (u >> 7) & 0xFF;
  bool sane = ((u & 0x7FFFu) == 0) || (e >= 107 && e <= 137);
  unsigned long long m = __ballot(sane);
  const int* ib = (const int*)idx_raw;
  int v = ib[2 * lane + 1];
  unsigned long long m2 = __ballot(v != 0);
  if (lane == 0) {
    hdr[0] = (__popcll(m) >= 32) ? 0 : 1;
    hdr[1] = (m2 == 0ull) ? 1 : 0;
  }
}

// ---------- weights -> bf16, biases -> f32 ----------
__global__ void convert_w_kernel(const void* __restrict__ W1l, const void* __restrict__ W1r,
                                 const void* __restrict__ W2l, const void* __restrict__ W2r,
                                 const void* __restrict__ b1, const void* __restrict__ b2,
                                 const int* __restrict__ hdr,
                                 unsigned short* __restrict__ W1l_h, unsigned short* __restrict__ W1r_h,
                                 unsigned short* __restrict__ W2l_h, unsigned short* __restrict__ W2r_h,
                                 float* __restrict__ b1_f, float* __restrict__ b2_f) {
  int i = blockIdx.x * blockDim.x + threadIdx.x;
  const void* s; unsigned short* dh = nullptr; float* df = nullptr; int off;
  if (i < 8192)       { s = W1l; dh = W1l_h; off = i; }
  else if (i < 16384) { s = W1r; dh = W1r_h; off = i - 8192; }
  else if (i < 32768) { s = W2l; dh = W2l_h; off = i - 16384; }
  else if (i < 49152) { s = W2r; dh = W2r_h; off = i - 32768; }
  else if (i < 49280) { s = b1;  df = b1_f;  off = i - 49152; }
  else if (i < 49408) { s = b2;  df = b2_f;  off = i - 49280; }
  else return;
  float v = hdr[0] ? ((const float*)s)[off] : b2f(((const unsigned short*)s)[off]);
  if (dh) dh[off] = f2b(v);  // identity when input already bf16
  else df[off] = v;
}

__global__ void convert_x_kernel(const void* __restrict__ x_raw,
                                 const int* __restrict__ hdr,
                                 unsigned short* __restrict__ xc, int n_elems) {
  int i = blockIdx.x * blockDim.x + threadIdx.x;
  if (i >= n_elems) return;
  xc[i] = hdr[0] ? f2b(((const float*)x_raw)[i]) : ((const unsigned short*)x_raw)[i];
}

// ---------- P1: per-chunk bucket histogram (LDS atomics only) ----------
__global__ __launch_bounds__(256) void hist_chunks_kernel(
    const int* __restrict__ idx_raw, const int* __restrict__ hdr,
    int* __restrict__ H, int n_edges, int NC) {
  __shared__ int h[NBUCKP];
  for (int i = threadIdx.x; i < NBUCKP; i += 256) h[i] = 0;
  __syncthreads();
  const int c = blockIdx.x;
  const bool i64 = hdr[1];
  const int base = c * CHUNK;
  #pragma unroll
  for (int t = 0; t < CHUNK / 256; ++t) {
    int e = base + t * 256 + threadIdx.x;
    if (e < n_edges) {
      int d = i64 ? idx_raw[2 * (n_edges + e)] : idx_raw[n_edges + e];
      atomicAdd(&h[d >> 7], 1);
    }
  }
  __syncthreads();
  for (int i = threadIdx.x; i < NBUCKP; i += 256) H[(size_t)i * NC + c] = h[i];
}

// ---------- P2: flat exclusive scan of H (NBUCKP*NC ints) ----------
__global__ __launch_bounds__(256) void gscan_sums_kernel(const int* __restrict__ arr,
                                                         int* __restrict__ blockSums, int n) {
  __shared__ int ws[4];
  int tid = threadIdx.x, lane = tid & 63, wid = tid >> 6;
  int base = blockIdx.x * 2048 + tid * 8;
  int s = 0;
  #pragma unroll
  for (int t = 0; t < 8; ++t) {
    int i = base + t;
    if (i < n) s += arr[i];
  }
  #pragma unroll
  for (int m = 1; m < 64; m <<= 1) s += __shfl_xor(s, m, 64);
  if (lane == 0) ws[wid] = s;
  __syncthreads();
  if (tid == 0) blockSums[blockIdx.x] = ws[0] + ws[1] + ws[2] + ws[3];
}

__global__ void gscan_offsets_kernel(const int* __restrict__ blockSums,
                                     int* __restrict__ blockOffs, int nb) {
  int lane = threadIdx.x;  // 64
  int carry = 0;
  for (int start = 0; start < nb; start += 64) {
    int i = start + lane;
    int v = (i < nb) ? blockSums[i] : 0;
    int isc = v;
    #pragma unroll
    for (int off = 1; off < 64; off <<= 1) {
      int t = __shfl_up(isc, off, 64);
      if (lane >= off) isc += t;
    }
    if (i < nb) blockOffs[i] = carry + isc - v;
    carry += __shfl(isc, 63, 64);
  }
}

__global__ __launch_bounds__(256) void gscan_emit_kernel(const int* __restrict__ arr,
                                                         const int* __restrict__ blockOffs,
                                                         int* __restrict__ out, int n) {
  __shared__ int ws[4];
  int tid = threadIdx.x, lane = tid & 63, wid = tid >> 6;
  int base = blockIdx.x * 2048 + tid * 8;
  int v[8];
  int s = 0;
  #pragma unroll
  for (int t = 0; t < 8; ++t) {
    int i = base + t;
    v[t] = (i < n) ? arr[i] : 0;
    s += v[t];
  }
  int isc = s;
  #pragma unroll
  for (int off = 1; off < 64; off <<= 1) {
    int t = __shfl_up(isc, off, 64);
    if (lane >= off) isc += t;
  }
  if (lane == 63) ws[wid] = isc;
  __syncthreads();
  int wb = 0;
  #pragma unroll
  for (int w = 0; w < 4; ++w)
    if (w < wid) wb += ws[w];
  int excl = blockOffs[blockIdx.x] + wb + isc - s;
  #pragma unroll
  for (int t = 0; t < 8; ++t) {
    int i = base + t;
    if (i < n) {
      out[i] = excl;
      excl += v[t];
    }
  }
}

// ---------- P3: scatter (src,dst) into bucket-sorted ebuf (no global atomics) ----------
__global__ __launch_bounds__(256) void scatter_kernel(
    const int* __restrict__ idx_raw, const int* __restrict__ hdr,
    const int* __restrict__ O, unsigned long long* __restrict__ ebuf,
    int n_edges, int NC) {
  __shared__ int base[NBUCKP];
  const int c = blockIdx.x;
  for (int i = threadIdx.x; i < NBUCKP; i += 256) base[i] = O[(size_t)i * NC + c];
  __syncthreads();
  const bool i64 = hdr[1];
  const int eb = c * CHUNK;
  #pragma unroll
  for (int t = 0; t < CHUNK / 256; ++t) {
    int e = eb + t * 256 + threadIdx.x;
    if (e < n_edges) {
      int s = i64 ? idx_raw[2 * e] : idx_raw[e];
      int d = i64 ? idx_raw[2 * (n_edges + e)] : idx_raw[n_edges + e];
      int pos = atomicAdd(&base[d >> 7], 1);  // LDS atomic
      ebuf[pos] = (unsigned long long)(unsigned)s | ((unsigned long long)(unsigned)d << 32);
    }
  }
}

// ---------- P4: per-bucket CSR finalize (contiguous segment, LDS only) ----------
__global__ __launch_bounds__(256) void bucket_csr_kernel(
    const unsigned long long* __restrict__ ebuf, const int* __restrict__ O,
    int* __restrict__ col, int* __restrict__ row_start, float* __restrict__ deg_inv,
    int n_nodes, int n_edges, int NC) {
  __shared__ int cntl[128];
  __shared__ int cur[128];
  __shared__ int w0tot;
  const int b = blockIdx.x, tid = threadIdx.x;
  const int node0 = b << 7;
  const int beg = O[(size_t)b * NC];
  const int end = (b + 1 < NBUCKP) ? O[(size_t)(b + 1) * NC] : n_edges;
  if (tid < 128) cntl[tid] = 0;
  __syncthreads();
  for (int e = beg + tid; e < end; e += 256) {
    int d = (int)(ebuf[e] >> 32);
    atomicAdd(&cntl[d - node0], 1);
  }
  __syncthreads();
  int v = (tid < 128) ? cntl[tid] : 0;
  int lane = tid & 63;
  int isc = v;
  #pragma unroll
  for (int o = 1; o < 64; o <<= 1) {
    int t = __shfl_up(isc, o, 64);
    if (lane >= o) isc += t;
  }
  if (tid == 63) w0tot = isc;
  __syncthreads();
  int incl = isc + ((tid >= 64 && tid < 128) ? w0tot : 0);
  int excl = incl - v;
  if (tid < 128) {
    cur[tid] = excl;
    int node = node0 + tid;
    if (node < n_nodes) {
      row_start[node] = beg + excl;
      deg_inv[node] = 1.0f / (float)((v > 1) ? v : 1);
    }
  }
  __syncthreads();
  for (int e = beg + tid; e < end; e += 256) {
    unsigned long long u = ebuf[e];
    int s = (int)(u & 0xFFFFFFFFull);
    int d = (int)(u >> 32);
    int r = atomicAdd(&cur[d - node0], 1);  // LDS atomic
    col[beg + r] = s;
  }
  if (b == 0 && tid == 0) row_start[n_nodes] = n_edges;
}

// ---------- vectorized mean-aggregation gathers ----------
__global__ __launch_bounds__(256) void gather1_kernel(
    const unsigned short* __restrict__ xc, const int* __restrict__ row_start,
    const int* __restrict__ col, const float* __restrict__ deg_inv,
    unsigned short* __restrict__ agg1, int n_nodes) {
  int lane = threadIdx.x & 63;
  int n = blockIdx.x * 4 + (threadIdx.x >> 6);
  if (n >= n_nodes) return;
  int rg = lane >> 3, fq = lane & 7;
  int beg = row_start[n], end = row_start[n + 1];
  float a[8];
  #pragma unroll
  for (int t = 0; t < 8; ++t) a[t] = 0.f;
  int i = beg;
  for (; i + 15 < end; i += 16) {
    int s0 = col[i + rg], s1 = col[i + 8 + rg];
    uint4 p = *(const uint4*)(xc + (size_t)s0 * 64 + fq * 8);
    uint4 q = *(const uint4*)(xc + (size_t)s1 * 64 + fq * 8);
    a[0] += b2f(p.x & 0xFFFF); a[1] += b2f(p.x >> 16);
    a[2] += b2f(p.y & 0xFFFF); a[3] += b2f(p.y >> 16);
    a[4] += b2f(p.z & 0xFFFF); a[5] += b2f(p.z >> 16);
    a[6] += b2f(p.w & 0xFFFF); a[7] += b2f(p.w >> 16);
    a[0] += b2f(q.x & 0xFFFF); a[1] += b2f(q.x >> 16);
    a[2] += b2f(q.y & 0xFFFF); a[3] += b2f(q.y >> 16);
    a[4] += b2f(q.z & 0xFFFF); a[5] += b2f(q.z >> 16);
    a[6] += b2f(q.w & 0xFFFF); a[7] += b2f(q.w >> 16);
  }
  for (; i < end; i += 8) {
    if (i + rg < end) {
      int s0 = col[i + rg];
      uint4 p = *(const uint4*)(xc + (size_t)s0 * 64 + fq * 8);
      a[0] += b2f(p.x & 0xFFFF); a[1] += b2f(p.x >> 16);
      a[2] += b2f(p.y & 0xFFFF); a[3] += b2f(p.y >> 16);
      a[4] += b2f(p.z & 0xFFFF); a[5] += b2f(p.z >> 16);
      a[6] += b2f(p.w & 0xFFFF); a[7] += b2f(p.w >> 16);
    }
  }
  #pragma unroll
  for (int m = 8; m < 64; m <<= 1)
    #pragma unroll
    for (int t = 0; t < 8; ++t) a[t] += __shfl_xor(a[t], m, 64);
  if (rg == 0) {
    float di = deg_inv[n];
    uint4 o;
    o.x = pack2(a[0] * di, a[1] * di);
    o.y = pack2(a[2] * di, a[3] * di);
    o.z = pack2(a[4] * di, a[5] * di);
    o.w = pack2(a[6] * di, a[7] * di);
    *(uint4*)(agg1 + (size_t)n * 64 + fq * 8) = o;
  }
}

__global__ __launch_bounds__(256) void gather2_kernel(
    const unsigned short* __restrict__ h, const int* __restrict__ row_start,
    const int* __restrict__ col, const float* __restrict__ deg_inv,
    unsigned short* __restrict__ agg2, int n_nodes) {
  int lane = threadIdx.x & 63;
  int n = blockIdx.x * 4 + (threadIdx.x >> 6);
  if (n >= n_nodes) return;
  int rg = lane >> 4, fq = lane & 15;
  int beg = row_start[n], end = row_start[n + 1];
  float a[8];
  #pragma unroll
  for (int t = 0; t < 8; ++t) a[t] = 0.f;
  int i = beg;
  for (; i + 7 < end; i += 8) {
    int s0 = col[i + rg], s1 = col[i + 4 + rg];
    uint4 p = *(const uint4*)(h + (size_t)s0 * 128 + fq * 8);
    uint4 q = *(const uint4*)(h + (size_t)s1 * 128 + fq * 8);
    a[0] += b2f(p.x & 0xFFFF); a[1] += b2f(p.x >> 16);
    a[2] += b2f(p.y & 0xFFFF); a[3] += b2f(p.y >> 16);
    a[4] += b2f(p.z & 0xFFFF); a[5] += b2f(p.z >> 16);
    a[6] += b2f(p.w & 0xFFFF); a[7] += b2f(p.w >> 16);
    a[0] += b2f(q.x & 0xFFFF); a[1] += b2f(q.x >> 16);
    a[2] += b2f(q.y & 0xFFFF); a[3] += b2f(q.y >> 16);
    a[4] += b2f(q.z & 0xFFFF); a[5] += b2f(q.z >> 16);
    a[6] += b2f(q.w & 0xFFFF); a[7] += b2f(q.w >> 16);
  }
  for (; i < end; i += 4) {
    if (i + rg < end) {
      int s0 = col[i + rg];
      uint4 p = *(const uint4*)(h + (size_t)s0 * 128 + fq * 8);
      a[0] += b2f(p.x & 0xFFFF); a[1] += b2f(p.x >> 16);
      a[2] += b2f(p.y & 0xFFFF); a[3] += b2f(p.y >> 16);
      a[4] += b2f(p.z & 0xFFFF); a[5] += b2f(p.z >> 16);
      a[6] += b2f(p.w & 0xFFFF); a[7] += b2f(p.w >> 16);
    }
  }
  #pragma unroll
  for (int m = 16; m < 64; m <<= 1)
    #pragma unroll
    for (int t = 0; t < 8; ++t) a[t] += __shfl_xor(a[t], m, 64);
  if (rg == 0) {
    float di = deg_inv[n];
    uint4 o;
    o.x = pack2(a[0] * di, a[1] * di);
    o.y = pack2(a[2] * di, a[3] * di);
    o.z = pack2(a[4] * di, a[5] * di);
    o.w = pack2(a[6] * di, a[7] * di);
    *(uint4*)(agg2 + (size_t)n * 128 + fq * 8) = o;
  }
}

// ---------- MFMA concat-GEMM: C = act([A1|A2] @ [Wl|Wr]^T + b) ----------
template <int K1, int K2, bool RELU, bool FINAL>
__global__ __launch_bounds__(256, 4) void gemm_mfma(
    const unsigned short* __restrict__ A1, const unsigned short* __restrict__ A2,
    const unsigned short* __restrict__ Wl, const unsigned short* __restrict__ Wr,
    const float* __restrict__ bias,
    unsigned short* __restrict__ Cb, void* __restrict__ Cf,
    const int* __restrict__ hdr, int n_nodes) {
  const int tid = threadIdx.x;
  const int wave = tid >> 6, lane = tid & 63;
  const int m16 = lane & 15, quad = lane >> 4;
  const int nb = blockIdx.x * 128 + wave * 32;
  int row0 = nb + m16;      if (row0 >= n_nodes) row0 = n_nodes - 1;
  int row1 = nb + 16 + m16; if (row1 >= n_nodes) row1 = n_nodes - 1;

  f32x4 acc[2][8];
  #pragma unroll
  for (int mi = 0; mi < 2; ++mi)
    #pragma unroll
    for (int ji = 0; ji < 8; ++ji) acc[mi][ji] = (f32x4){0.f, 0.f, 0.f, 0.f};

  constexpr int NSTEP = (K1 + K2) / 32;
  #pragma unroll
  for (int c = 0; c < NSTEP; ++c) {
    const bool first = (c * 32) < K1;
    const unsigned short* A = first ? A1 : A2;
    const unsigned short* W = first ? Wl : Wr;
    const int kb = first ? c * 32 : c * 32 - K1;
    const int Krow = first ? K1 : K2;
    const int ko = kb + quad * 8;
    bf16x8 a0 = *(const bf16x8*)(A + (size_t)row0 * Krow + ko);
    bf16x8 a1 = *(const bf16x8*)(A + (size_t)row1 * Krow + ko);
    bf16x8 w[8];
    #pragma unroll
    for (int ji = 0; ji < 8; ++ji)
      w[ji] = *(const bf16x8*)(W + (size_t)(ji * 16 + m16) * Krow + ko);
    #pragma unroll
    for (int ji = 0; ji < 8; ++ji) {
      acc[0][ji] = __builtin_amdgcn_mfma_f32_16x16x32_bf16(a0, w[ji], acc[0][ji], 0, 0, 0);
      acc[1][ji] = __builtin_amdgcn_mfma_f32_16x16x32_bf16(a1, w[ji], acc[1][ji], 0, 0, 0);
    }
  }

  const bool f32out = FINAL && (hdr[0] == 1);
  #pragma unroll
  for (int ji = 0; ji < 8; ++ji) {
    int j = ji * 16 + m16;
    float bj = bias[j];
    #pragma unroll
    for (int mi = 0; mi < 2; ++mi) {
      #pragma unroll
      for (int r = 0; r < 4; ++r) {
        int n = nb + mi * 16 + quad * 4 + r;
        if (n >= n_nodes) continue;
        float v = acc[mi][ji][r] + bj;
        if (RELU) v = fmaxf(v, 0.f);
        if (FINAL) {
          if (f32out) ((float*)Cf)[(size_t)n * 128 + j] = v;
          else ((unsigned short*)Cf)[(size_t)n * 128 + j] = f2b(v);
        } else {
          Cb[(size_t)n * 128 + j] = f2b(v);
        }
      }
    }
  }
}

// ---------- launch ----------
extern "C" void kernel_launch(void* const* d_in, const int* in_sizes, int n_in,
                              void* d_out, int out_size, void* d_ws, size_t ws_size,
                              hipStream_t stream) {
  const void* x_raw  = d_in[0];
  const int* idx_raw = (const int*)d_in[1];
  const void* W1l = d_in[2];
  const void* b1  = d_in[3];
  const void* W1r = d_in[4];
  const void* W2l = d_in[5];
  const void* b2  = d_in[6];
  const void* W2r = d_in[7];
  const int N = in_sizes[0] / 64;
  const int E = in_sizes[1] / 2;
  const int NC = (E + CHUNK - 1) / CHUNK;
  const int NSCAN = NBUCKP * NC;
  const int NBs = (NSCAN + 2047) / 2048;
  const int NBUCK = (N + 127) >> 7;

  char* ws = (char*)d_ws;
  size_t off = 0;
  auto alloc = [&](size_t bytes) {
    char* p = ws + off;
    off = (off + bytes + 511) & ~((size_t)511);
    return p;
  };
  int* hdr        = (int*)alloc(512);
  int* H          = (int*)alloc((size_t)NSCAN * 4);
  int* O          = (int*)alloc((size_t)NSCAN * 4);
  int* blockSums  = (int*)alloc((size_t)NBs * 4);
  int* blockOffs  = (int*)alloc((size_t)NBs * 4);
  unsigned long long* ebuf = (unsigned long long*)alloc((size_t)E * 8);
  int* col        = (int*)alloc((size_t)E * 4);
  int* row_start  = (int*)alloc(((size_t)N + 1) * 4);
  float* deg_inv  = (float*)alloc((size_t)N * 4);
  unsigned short* W1l_h = (unsigned short*)alloc(16384);
  unsigned short* W1r_h = (unsigned short*)alloc(16384);
  unsigned short* W2l_h = (unsigned short*)alloc(32768);
  unsigned short* W2r_h = (unsigned short*)alloc(32768);
  float* b1_f     = (float*)alloc(512);
  float* b2_f     = (float*)alloc(512);
  unsigned short* xc   = (unsigned short*)alloc((size_t)N * 64 * 2);
  unsigned short* agg1 = (unsigned short*)alloc((size_t)N * 64 * 2);
  unsigned short* hbuf = (unsigned short*)alloc((size_t)N * 128 * 2);
  unsigned short* agg2 = (unsigned short*)alloc((size_t)N * 128 * 2);

  detect_kernel<<<1, 64, 0, stream>>>(x_raw, idx_raw, hdr);
  convert_w_kernel<<<(49408 + 255) / 256, 256, 0, stream>>>(
      W1l, W1r, W2l, W2r, b1, b2, hdr, W1l_h, W1r_h, W2l_h, W2r_h, b1_f, b2_f);
  convert_x_kernel<<<(N * 64 + 255) / 256, 256, 0, stream>>>(x_raw, hdr, xc, N * 64);
  hist_chunks_kernel<<<NC, 256, 0, stream>>>(idx_raw, hdr, H, E, NC);
  gscan_sums_kernel<<<NBs, 256, 0, stream>>>(H, blockSums, NSCAN);
  gscan_offsets_kernel<<<1, 64, 0, stream>>>(blockSums, blockOffs, NBs);
  gscan_emit_kernel<<<NBs, 256, 0, stream>>>(H, blockOffs, O, NSCAN);
  scatter_kernel<<<NC, 256, 0, stream>>>(idx_raw, hdr, O, ebuf, E, NC);
  bucket_csr_kernel<<<NBUCK, 256, 0, stream>>>(ebuf, O, col, row_start, deg_inv, N, E, NC);
  gather1_kernel<<<(N + 3) / 4, 256, 0, stream>>>(xc, row_start, col, deg_inv, agg1, N);
  gemm_mfma<64, 64, true, false><<<(N + 127) / 128, 256, 0, stream>>>(
      agg1, xc, W1l_h, W1r_h, b1_f, hbuf, nullptr, hdr, N);
  gather2_kernel<<<(N + 3) / 4, 256, 0, stream>>>(hbuf, row_start, col, deg_inv, agg2, N);
  gemm_mfma<128, 128, false, true><<<(N + 127) / 128, 256, 0, stream>>>(
      agg2, hbuf, W2l_h, W2r_h, b2_f, nullptr, d_out, hdr, N);
}

// Round 6
// 331.790 us; speedup vs baseline: 2.5382x; 1.0202x over previous
//
#include <hip/hip_runtime.h>
#include <hip/hip_bf16.h>

// ---------- helpers ----------
__device__ __forceinline__ float b2f(unsigned short u) {
  return __uint_as_float(((unsigned int)u) << 16);
}
__device__ __forceinline__ unsigned short f2b(float f) {
  unsigned int x = __float_as_uint(f);
  unsigned int r = x + 0x7FFFu + ((x >> 16) & 1u);  // RNE
  return (unsigned short)(r >> 16);
}
__device__ __forceinline__ unsigned int pack2(float lo, float hi) {
  return (unsigned int)f2b(lo) | ((unsigned int)f2b(hi) << 16);
}
// accumulate 8 bf16 (one uint4) into a[0..7]; even idx = low half, odd = high.
// hi unpack via and-mask (exact bf16 value), 1 VALU op each.
__device__ __forceinline__ void acc8(float* a, uint4 p) {
  a[0] += __uint_as_float(p.x << 16); a[1] += __uint_as_float(p.x & 0xFFFF0000u);
  a[2] += __uint_as_float(p.y << 16); a[3] += __uint_as_float(p.y & 0xFFFF0000u);
  a[4] += __uint_as_float(p.z << 16); a[5] += __uint_as_float(p.z & 0xFFFF0000u);
  a[6] += __uint_as_float(p.w << 16); a[7] += __uint_as_float(p.w & 0xFFFF0000u);
}

typedef short bf16x8 __attribute__((ext_vector_type(8)));  // 8 bf16 = 4 VGPRs
typedef float f32x4 __attribute__((ext_vector_type(4)));

#define CHUNK 8192          // edges per P1/P3 block
#define NBUCKP 1024         // padded bucket count (bucket = dst >> 7, N <= 131072)

// ---------- dtype detection ----------
// hdr[0]: 0 = floats are bf16, 1 = floats are f32
// hdr[1]: 0 = edge_index int32, 1 = int64
__global__ void detect_kernel(const void* __restrict__ x_raw,
                              const void* __restrict__ idx_raw,
                              int* __restrict__ hdr) {
  int lane = threadIdx.x;  // 64 threads
  const unsigned short* xb = (const unsigned short*)x_raw;
  unsigned short u = xb[2 * lane];
  int e = (u >> 7) & 0xFF;
  bool sane = ((u & 0x7FFFu) == 0) || (e >= 107 && e <= 137);
  unsigned long long m = __ballot(sane);
  const int* ib = (const int*)idx_raw;
  int v = ib[2 * lane + 1];
  unsigned long long m2 = __ballot(v != 0);
  if (lane == 0) {
    hdr[0] = (__popcll(m) >= 32) ? 0 : 1;
    hdr[1] = (m2 == 0ull) ? 1 : 0;
  }
}

// ---------- weights -> bf16, biases -> f32 ----------
__global__ void convert_w_kernel(const void* __restrict__ W1l, const void* __restrict__ W1r,
                                 const void* __restrict__ W2l, const void* __restrict__ W2r,
                                 const void* __restrict__ b1, const void* __restrict__ b2,
                                 const int* __restrict__ hdr,
                                 unsigned short* __restrict__ W1l_h, unsigned short* __restrict__ W1r_h,
                                 unsigned short* __restrict__ W2l_h, unsigned short* __restrict__ W2r_h,
                                 float* __restrict__ b1_f, float* __restrict__ b2_f) {
  int i = blockIdx.x * blockDim.x + threadIdx.x;
  const void* s; unsigned short* dh = nullptr; float* df = nullptr; int off;
  if (i < 8192)       { s = W1l; dh = W1l_h; off = i; }
  else if (i < 16384) { s = W1r; dh = W1r_h; off = i - 8192; }
  else if (i < 32768) { s = W2l; dh = W2l_h; off = i - 16384; }
  else if (i < 49152) { s = W2r; dh = W2r_h; off = i - 32768; }
  else if (i < 49280) { s = b1;  df = b1_f;  off = i - 49152; }
  else if (i < 49408) { s = b2;  df = b2_f;  off = i - 49280; }
  else return;
  float v = hdr[0] ? ((const float*)s)[off] : b2f(((const unsigned short*)s)[off]);
  if (dh) dh[off] = f2b(v);  // identity when input already bf16
  else df[off] = v;
}

__global__ void convert_x_kernel(const void* __restrict__ x_raw,
                                 const int* __restrict__ hdr,
                                 unsigned short* __restrict__ xc, int n_elems) {
  int i = blockIdx.x * blockDim.x + threadIdx.x;
  if (i >= n_elems) return;
  xc[i] = hdr[0] ? f2b(((const float*)x_raw)[i]) : ((const unsigned short*)x_raw)[i];
}

// ---------- P1: per-chunk bucket histogram (LDS atomics, uint4 idx reads) ----------
__global__ __launch_bounds__(256) void hist_chunks_kernel(
    const int* __restrict__ idx_raw, const int* __restrict__ hdr,
    int* __restrict__ H, int n_edges, int NC) {
  __shared__ int h[NBUCKP];
  for (int i = threadIdx.x; i < NBUCKP; i += 256) h[i] = 0;
  __syncthreads();
  const int c = blockIdx.x;
  const int base = c * CHUNK;
  const int lim = min(n_edges - base, CHUNK);
  if (hdr[1]) {  // int64: dst int64 stream at int-offset 2*n_edges + 2e
    const uint4* dp = (const uint4*)(idx_raw + 2 * (size_t)n_edges + 2 * (size_t)base);
    #pragma unroll
    for (int t = 0; t < CHUNK / 512; ++t) {
      int q = t * 256 + threadIdx.x;
      int e = 2 * q;
      if (e < lim) {
        uint4 v = dp[q];
        atomicAdd(&h[((int)v.x) >> 7], 1);
        if (e + 1 < lim) atomicAdd(&h[((int)v.z) >> 7], 1);
      }
    }
  } else {       // int32: dst stream at int-offset n_edges + e
    const uint4* dp = (const uint4*)(idx_raw + (size_t)n_edges + base);
    #pragma unroll
    for (int t = 0; t < CHUNK / 1024; ++t) {
      int q = t * 256 + threadIdx.x;
      int e = 4 * q;
      if (e < lim) {
        uint4 v = dp[q];
        atomicAdd(&h[((int)v.x) >> 7], 1);
        if (e + 1 < lim) atomicAdd(&h[((int)v.y) >> 7], 1);
        if (e + 2 < lim) atomicAdd(&h[((int)v.z) >> 7], 1);
        if (e + 3 < lim) atomicAdd(&h[((int)v.w) >> 7], 1);
      }
    }
  }
  __syncthreads();
  for (int i = threadIdx.x; i < NBUCKP; i += 256) H[(size_t)i * NC + c] = h[i];
}

// ---------- P2: flat exclusive scan of H (NBUCKP*NC ints) ----------
__global__ __launch_bounds__(256) void gscan_sums_kernel(const int* __restrict__ arr,
                                                         int* __restrict__ blockSums, int n) {
  __shared__ int ws[4];
  int tid = threadIdx.x, lane = tid & 63, wid = tid >> 6;
  int base = blockIdx.x * 2048 + tid * 8;
  int s = 0;
  #pragma unroll
  for (int t = 0; t < 8; ++t) {
    int i = base + t;
    if (i < n) s += arr[i];
  }
  #pragma unroll
  for (int m = 1; m < 64; m <<= 1) s += __shfl_xor(s, m, 64);
  if (lane == 0) ws[wid] = s;
  __syncthreads();
  if (tid == 0) blockSums[blockIdx.x] = ws[0] + ws[1] + ws[2] + ws[3];
}

__global__ void gscan_offsets_kernel(const int* __restrict__ blockSums,
                                     int* __restrict__ blockOffs, int nb) {
  int lane = threadIdx.x;  // 64
  int carry = 0;
  for (int start = 0; start < nb; start += 64) {
    int i = start + lane;
    int v = (i < nb) ? blockSums[i] : 0;
    int isc = v;
    #pragma unroll
    for (int off = 1; off < 64; off <<= 1) {
      int t = __shfl_up(isc, off, 64);
      if (lane >= off) isc += t;
    }
    if (i < nb) blockOffs[i] = carry + isc - v;
    carry += __shfl(isc, 63, 64);
  }
}

__global__ __launch_bounds__(256) void gscan_emit_kernel(const int* __restrict__ arr,
                                                         const int* __restrict__ blockOffs,
                                                         int* __restrict__ out, int n) {
  __shared__ int ws[4];
  int tid = threadIdx.x, lane = tid & 63, wid = tid >> 6;
  int base = blockIdx.x * 2048 + tid * 8;
  int v[8];
  int s = 0;
  #pragma unroll
  for (int t = 0; t < 8; ++t) {
    int i = base + t;
    v[t] = (i < n) ? arr[i] : 0;
    s += v[t];
  }
  int isc = s;
  #pragma unroll
  for (int off = 1; off < 64; off <<= 1) {
    int t = __shfl_up(isc, off, 64);
    if (lane >= off) isc += t;
  }
  if (lane == 63) ws[wid] = isc;
  __syncthreads();
  int wb = 0;
  #pragma unroll
  for (int w = 0; w < 4; ++w)
    if (w < wid) wb += ws[w];
  int excl = blockOffs[blockIdx.x] + wb + isc - s;
  #pragma unroll
  for (int t = 0; t < 8; ++t) {
    int i = base + t;
    if (i < n) {
      out[i] = excl;
      excl += v[t];
    }
  }
}

// ---------- P3: scatter (src,dst) into bucket-sorted ebuf (uint4 idx reads) ----------
__global__ __launch_bounds__(256) void scatter_kernel(
    const int* __restrict__ idx_raw, const int* __restrict__ hdr,
    const int* __restrict__ O, unsigned long long* __restrict__ ebuf,
    int n_edges, int NC) {
  __shared__ int base[NBUCKP];
  const int c = blockIdx.x;
  for (int i = threadIdx.x; i < NBUCKP; i += 256) base[i] = O[(size_t)i * NC + c];
  __syncthreads();
  const int eb = c * CHUNK;
  const int lim = min(n_edges - eb, CHUNK);
  if (hdr[1]) {
    const uint4* sp = (const uint4*)(idx_raw + 2 * (size_t)eb);
    const uint4* dp = (const uint4*)(idx_raw + 2 * (size_t)n_edges + 2 * (size_t)eb);
    #pragma unroll
    for (int t = 0; t < CHUNK / 512; ++t) {
      int q = t * 256 + threadIdx.x;
      int e = 2 * q;
      if (e < lim) {
        uint4 sv = sp[q], dv = dp[q];
        int p0 = atomicAdd(&base[((int)dv.x) >> 7], 1);
        ebuf[p0] = (unsigned long long)sv.x | ((unsigned long long)dv.x << 32);
        if (e + 1 < lim) {
          int p1 = atomicAdd(&base[((int)dv.z) >> 7], 1);
          ebuf[p1] = (unsigned long long)sv.z | ((unsigned long long)dv.z << 32);
        }
      }
    }
  } else {
    const uint4* sp = (const uint4*)(idx_raw + (size_t)eb);
    const uint4* dp = (const uint4*)(idx_raw + (size_t)n_edges + eb);
    #pragma unroll
    for (int t = 0; t < CHUNK / 1024; ++t) {
      int q = t * 256 + threadIdx.x;
      int e = 4 * q;
      if (e < lim) {
        uint4 sv = sp[q], dv = dp[q];
        int p0 = atomicAdd(&base[((int)dv.x) >> 7], 1);
        ebuf[p0] = (unsigned long long)sv.x | ((unsigned long long)dv.x << 32);
        if (e + 1 < lim) {
          int p1 = atomicAdd(&base[((int)dv.y) >> 7], 1);
          ebuf[p1] = (unsigned long long)sv.y | ((unsigned long long)dv.y << 32);
        }
        if (e + 2 < lim) {
          int p2 = atomicAdd(&base[((int)dv.z) >> 7], 1);
          ebuf[p2] = (unsigned long long)sv.z | ((unsigned long long)dv.z << 32);
        }
        if (e + 3 < lim) {
          int p3 = atomicAdd(&base[((int)dv.w) >> 7], 1);
          ebuf[p3] = (unsigned long long)sv.w | ((unsigned long long)dv.w << 32);
        }
      }
    }
  }
}

// ---------- P4: per-bucket CSR finalize (contiguous segment, LDS only) ----------
__global__ __launch_bounds__(256) void bucket_csr_kernel(
    const unsigned long long* __restrict__ ebuf, const int* __restrict__ O,
    int* __restrict__ col, int* __restrict__ row_start, float* __restrict__ deg_inv,
    int n_nodes, int n_edges, int NC) {
  __shared__ int cntl[128];
  __shared__ int cur[128];
  __shared__ int w0tot;
  const int b = blockIdx.x, tid = threadIdx.x;
  const int node0 = b << 7;
  const int beg = O[(size_t)b * NC];
  const int end = (b + 1 < NBUCKP) ? O[(size_t)(b + 1) * NC] : n_edges;
  if (tid < 128) cntl[tid] = 0;
  __syncthreads();
  for (int e = beg + tid; e < end; e += 256) {
    int d = (int)(ebuf[e] >> 32);
    atomicAdd(&cntl[d - node0], 1);
  }
  __syncthreads();
  int v = (tid < 128) ? cntl[tid] : 0;
  int lane = tid & 63;
  int isc = v;
  #pragma unroll
  for (int o = 1; o < 64; o <<= 1) {
    int t = __shfl_up(isc, o, 64);
    if (lane >= o) isc += t;
  }
  if (tid == 63) w0tot = isc;
  __syncthreads();
  int incl = isc + ((tid >= 64 && tid < 128) ? w0tot : 0);
  int excl = incl - v;
  if (tid < 128) {
    cur[tid] = excl;
    int node = node0 + tid;
    if (node < n_nodes) {
      row_start[node] = beg + excl;
      deg_inv[node] = 1.0f / (float)((v > 1) ? v : 1);
    }
  }
  __syncthreads();
  for (int e = beg + tid; e < end; e += 256) {
    unsigned long long u = ebuf[e];
    int s = (int)(u & 0xFFFFFFFFull);
    int d = (int)(u >> 32);
    int r = atomicAdd(&cur[d - node0], 1);  // LDS atomic
    col[beg + r] = s;
  }
  if (b == 0 && tid == 0) row_start[n_nodes] = n_edges;
}

// ---------- gather1: 2 nodes/wave, 4 row-loads in flight ----------
// Row = 64 bf16 = 128B = 8 uint4. Per node: 32 lanes, rg=(lane&31)>>3 (4 edge
// slots), fq=lane&7 (8 features each). Typical deg-16 node = one 16-edge
// iteration with 4 loads issued back-to-back.
__global__ __launch_bounds__(256) void gather1_kernel(
    const unsigned short* __restrict__ xc, const int* __restrict__ row_start,
    const int* __restrict__ col, const float* __restrict__ deg_inv,
    unsigned short* __restrict__ agg1, int n_nodes) {
  int lane = threadIdx.x & 63;
  int n = blockIdx.x * 8 + (threadIdx.x >> 6) * 2 + (lane >> 5);
  if (n >= n_nodes) return;
  int l32 = lane & 31;
  int rg = l32 >> 3, fq = l32 & 7;
  int beg = row_start[n], end = row_start[n + 1];
  float a[8];
  #pragma unroll
  for (int t = 0; t < 8; ++t) a[t] = 0.f;
  int i = beg;
  for (; i + 15 < end; i += 16) {  // 16 edges, 4 loads in flight
    int s0 = col[i + rg], s1 = col[i + 4 + rg], s2 = col[i + 8 + rg], s3 = col[i + 12 + rg];
    uint4 p0 = *(const uint4*)(xc + (size_t)s0 * 64 + fq * 8);
    uint4 p1 = *(const uint4*)(xc + (size_t)s1 * 64 + fq * 8);
    uint4 p2 = *(const uint4*)(xc + (size_t)s2 * 64 + fq * 8);
    uint4 p3 = *(const uint4*)(xc + (size_t)s3 * 64 + fq * 8);
    acc8(a, p0); acc8(a, p1); acc8(a, p2); acc8(a, p3);
  }
  for (; i + 3 < end; i += 4) {
    int s0 = col[i + rg];
    uint4 p0 = *(const uint4*)(xc + (size_t)s0 * 64 + fq * 8);
    acc8(a, p0);
  }
  if (i + rg < end) {
    int s0 = col[i + rg];
    uint4 p0 = *(const uint4*)(xc + (size_t)s0 * 64 + fq * 8);
    acc8(a, p0);
  }
  #pragma unroll
  for (int m = 8; m <= 16; m <<= 1)   // reduce over 4 edge slots (within 32-lane half)
    #pragma unroll
    for (int t = 0; t < 8; ++t) a[t] += __shfl_xor(a[t], m, 64);
  if (rg == 0) {
    float di = deg_inv[n];
    uint4 o;
    o.x = pack2(a[0] * di, a[1] * di);
    o.y = pack2(a[2] * di, a[3] * di);
    o.z = pack2(a[4] * di, a[5] * di);
    o.w = pack2(a[6] * di, a[7] * di);
    *(uint4*)(agg1 + (size_t)n * 64 + fq * 8) = o;
  }
}

// ---------- gather2: 1 node/wave, 4 row-loads (16 edges) in flight ----------
// Row = 128 bf16 = 256B = 16 uint4. rg=lane>>4 (4 edge slots), fq=lane&15.
__global__ __launch_bounds__(256) void gather2_kernel(
    const unsigned short* __restrict__ h, const int* __restrict__ row_start,
    const int* __restrict__ col, const float* __restrict__ deg_inv,
    unsigned short* __restrict__ agg2, int n_nodes) {
  int lane = threadIdx.x & 63;
  int n = blockIdx.x * 4 + (threadIdx.x >> 6);
  if (n >= n_nodes) return;
  int rg = lane >> 4, fq = lane & 15;
  int beg = row_start[n], end = row_start[n + 1];
  float a[8];
  #pragma unroll
  for (int t = 0; t < 8; ++t) a[t] = 0.f;
  int i = beg;
  for (; i + 15 < end; i += 16) {  // 16 edges, 4 loads in flight
    int s0 = col[i + rg], s1 = col[i + 4 + rg], s2 = col[i + 8 + rg], s3 = col[i + 12 + rg];
    uint4 p0 = *(const uint4*)(h + (size_t)s0 * 128 + fq * 8);
    uint4 p1 = *(const uint4*)(h + (size_t)s1 * 128 + fq * 8);
    uint4 p2 = *(const uint4*)(h + (size_t)s2 * 128 + fq * 8);
    uint4 p3 = *(const uint4*)(h + (size_t)s3 * 128 + fq * 8);
    acc8(a, p0); acc8(a, p1); acc8(a, p2); acc8(a, p3);
  }
  for (; i + 3 < end; i += 4) {
    int s0 = col[i + rg];
    uint4 p0 = *(const uint4*)(h + (size_t)s0 * 128 + fq * 8);
    acc8(a, p0);
  }
  if (i + rg < end) {
    int s0 = col[i + rg];
    uint4 p0 = *(const uint4*)(h + (size_t)s0 * 128 + fq * 8);
    acc8(a, p0);
  }
  #pragma unroll
  for (int m = 16; m < 64; m <<= 1)
    #pragma unroll
    for (int t = 0; t < 8; ++t) a[t] += __shfl_xor(a[t], m, 64);
  if (rg == 0) {
    float di = deg_inv[n];
    uint4 o;
    o.x = pack2(a[0] * di, a[1] * di);
    o.y = pack2(a[2] * di, a[3] * di);
    o.z = pack2(a[4] * di, a[5] * di);
    o.w = pack2(a[6] * di, a[7] * di);
    *(uint4*)(agg2 + (size_t)n * 128 + fq * 8) = o;
  }
}

// ---------- MFMA concat-GEMM: C = act([A1|A2] @ [Wl|Wr]^T + b) ----------
template <int K1, int K2, bool RELU, bool FINAL>
__global__ __launch_bounds__(256, 4) void gemm_mfma(
    const unsigned short* __restrict__ A1, const unsigned short* __restrict__ A2,
    const unsigned short* __restrict__ Wl, const unsigned short* __restrict__ Wr,
    const float* __restrict__ bias,
    unsigned short* __restrict__ Cb, void* __restrict__ Cf,
    const int* __restrict__ hdr, int n_nodes) {
  const int tid = threadIdx.x;
  const int wave = tid >> 6, lane = tid & 63;
  const int m16 = lane & 15, quad = lane >> 4;
  const int nb = blockIdx.x * 128 + wave * 32;
  int row0 = nb + m16;      if (row0 >= n_nodes) row0 = n_nodes - 1;
  int row1 = nb + 16 + m16; if (row1 >= n_nodes) row1 = n_nodes - 1;

  f32x4 acc[2][8];
  #pragma unroll
  for (int mi = 0; mi < 2; ++mi)
    #pragma unroll
    for (int ji = 0; ji < 8; ++ji) acc[mi][ji] = (f32x4){0.f, 0.f, 0.f, 0.f};

  constexpr int NSTEP = (K1 + K2) / 32;
  #pragma unroll
  for (int c = 0; c < NSTEP; ++c) {
    const bool first = (c * 32) < K1;
    const unsigned short* A = first ? A1 : A2;
    const unsigned short* W = first ? Wl : Wr;
    const int kb = first ? c * 32 : c * 32 - K1;
    const int Krow = first ? K1 : K2;
    const int ko = kb + quad * 8;
    bf16x8 a0 = *(const bf16x8*)(A + (size_t)row0 * Krow + ko);
    bf16x8 a1 = *(const bf16x8*)(A + (size_t)row1 * Krow + ko);
    bf16x8 w[8];
    #pragma unroll
    for (int ji = 0; ji < 8; ++ji)
      w[ji] = *(const bf16x8*)(W + (size_t)(ji * 16 + m16) * Krow + ko);
    #pragma unroll
    for (int ji = 0; ji < 8; ++ji) {
      acc[0][ji] = __builtin_amdgcn_mfma_f32_16x16x32_bf16(a0, w[ji], acc[0][ji], 0, 0, 0);
      acc[1][ji] = __builtin_amdgcn_mfma_f32_16x16x32_bf16(a1, w[ji], acc[1][ji], 0, 0, 0);
    }
  }

  const bool f32out = FINAL && (hdr[0] == 1);
  #pragma unroll
  for (int ji = 0; ji < 8; ++ji) {
    int j = ji * 16 + m16;
    float bj = bias[j];
    #pragma unroll
    for (int mi = 0; mi < 2; ++mi) {
      #pragma unroll
      for (int r = 0; r < 4; ++r) {
        int n = nb + mi * 16 + quad * 4 + r;
        if (n >= n_nodes) continue;
        float v = acc[mi][ji][r] + bj;
        if (RELU) v = fmaxf(v, 0.f);
        if (FINAL) {
          if (f32out) ((float*)Cf)[(size_t)n * 128 + j] = v;
          else ((unsigned short*)Cf)[(size_t)n * 128 + j] = f2b(v);
        } else {
          Cb[(size_t)n * 128 + j] = f2b(v);
        }
      }
    }
  }
}

// ---------- launch ----------
extern "C" void kernel_launch(void* const* d_in, const int* in_sizes, int n_in,
                              void* d_out, int out_size, void* d_ws, size_t ws_size,
                              hipStream_t stream) {
  const void* x_raw  = d_in[0];
  const int* idx_raw = (const int*)d_in[1];
  const void* W1l = d_in[2];
  const void* b1  = d_in[3];
  const void* W1r = d_in[4];
  const void* W2l = d_in[5];
  const void* b2  = d_in[6];
  const void* W2r = d_in[7];
  const int N = in_sizes[0] / 64;
  const int E = in_sizes[1] / 2;
  const int NC = (E + CHUNK - 1) / CHUNK;
  const int NSCAN = NBUCKP * NC;
  const int NBs = (NSCAN + 2047) / 2048;
  const int NBUCK = (N + 127) >> 7;

  char* ws = (char*)d_ws;
  size_t off = 0;
  auto alloc = [&](size_t bytes) {
    char* p = ws + off;
    off = (off + bytes + 511) & ~((size_t)511);
    return p;
  };
  int* hdr        = (int*)alloc(512);
  int* H          = (int*)alloc((size_t)NSCAN * 4);
  int* O          = (int*)alloc((size_t)NSCAN * 4);
  int* blockSums  = (int*)alloc((size_t)NBs * 4);
  int* blockOffs  = (int*)alloc((size_t)NBs * 4);
  unsigned long long* ebuf = (unsigned long long*)alloc((size_t)E * 8);
  int* col        = (int*)alloc((size_t)E * 4);
  int* row_start  = (int*)alloc(((size_t)N + 1) * 4);
  float* deg_inv  = (float*)alloc((size_t)N * 4);
  unsigned short* W1l_h = (unsigned short*)alloc(16384);
  unsigned short* W1r_h = (unsigned short*)alloc(16384);
  unsigned short* W2l_h = (unsigned short*)alloc(32768);
  unsigned short* W2r_h = (unsigned short*)alloc(32768);
  float* b1_f     = (float*)alloc(512);
  float* b2_f     = (float*)alloc(512);
  unsigned short* xc   = (unsigned short*)alloc((size_t)N * 64 * 2);
  unsigned short* agg1 = (unsigned short*)alloc((size_t)N * 64 * 2);
  unsigned short* hbuf = (unsigned short*)alloc((size_t)N * 128 * 2);
  unsigned short* agg2 = (unsigned short*)alloc((size_t)N * 128 * 2);

  detect_kernel<<<1, 64, 0, stream>>>(x_raw, idx_raw, hdr);
  convert_w_kernel<<<(49408 + 255) / 256, 256, 0, stream>>>(
      W1l, W1r, W2l, W2r, b1, b2, hdr, W1l_h, W1r_h, W2l_h, W2r_h, b1_f, b2_f);
  convert_x_kernel<<<(N * 64 + 255) / 256, 256, 0, stream>>>(x_raw, hdr, xc, N * 64);
  hist_chunks_kernel<<<NC, 256, 0, stream>>>(idx_raw, hdr, H, E, NC);
  gscan_sums_kernel<<<NBs, 256, 0, stream>>>(H, blockSums, NSCAN);
  gscan_offsets_kernel<<<1, 64, 0, stream>>>(blockSums, blockOffs, NBs);
  gscan_emit_kernel<<<NBs, 256, 0, stream>>>(H, blockOffs, O, NSCAN);
  scatter_kernel<<<NC, 256, 0, stream>>>(idx_raw, hdr, O, ebuf, E, NC);
  bucket_csr_kernel<<<NBUCK, 256, 0, stream>>>(ebuf, O, col, row_start, deg_inv, N, E, NC);
  gather1_kernel<<<(N + 7) / 8, 256, 0, stream>>>(xc, row_start, col, deg_inv, agg1, N);
  gemm_mfma<64, 64, true, false><<<(N + 127) / 128, 256, 0, stream>>>(
      agg1, xc, W1l_h, W1r_h, b1_f, hbuf, nullptr, hdr, N);
  gather2_kernel<<<(N + 3) / 4, 256, 0, stream>>>(hbuf, row_start, col, deg_inv, agg2, N);
  gemm_mfma<128, 128, false, true><<<(N + 127) / 128, 256, 0, stream>>>(
      agg2, hbuf, W2l_h, W2r_h, b2_f, nullptr, d_out, hdr, N);
}